// Round 11
// baseline (1121.060 us; speedup 1.0000x reference)
//
#include <hip/hip_runtime.h>
#include <math.h>

// Problem constants: B=2, C=512, H=8 heads, dh=64, N=4096, Kmax=32
#define XSTRIDE  2097152u  // 512*4096 per-batch stride of x / out
#define G1STRIDE 524288u   // 128*4096

typedef _Float16 f16;
typedef f16   f16x8  __attribute__((ext_vector_type(8)));
typedef float f32x16 __attribute__((ext_vector_type(16)));
typedef unsigned int u32;
typedef unsigned short u16;

// ws layout (float offsets). Total 13,639,680 floats = 54.56 MB.
// CV lives in d_out: memset NaN -> select writes -> merge reads -> proj
// overwrites d_out. d_out also hosts XTH/XTL (16 MB) BEFORE the memset.
// merge emits OH/OL (f16 hi/lo, [b*4096+n][c=h*64+d]) overlaid on QH/QL
// (Q dead after select); proj_gemm consumes them on the matrix pipe.
#define WS_QH 0u          // f16 [2][8][4096][64]; later OH f16 [8192][512]
#define WS_QL 2097152u    // f16 lo parts; later OL
#define WS_KH 4194304u
#define WS_KL 6291456u
#define WS_VB 8388608u    // f16 V
#define WS_G1 10485760u   // f32 [2][128][4096]
#define WS_KD 11534336u   // int [2][4096]
#define WS_CI 11542528u   // u16 [65536 rows][64 slots]

// ---------------------------------------------------------------------------
// R17: gate1 GEMM with 128x32 N-tiles -> grid (128,1,2) = 256 blocks = 1/CU.
// Accumulation chain identical to the original -> G1 bitwise-identical.
// ---------------------------------------------------------------------------
__global__ __launch_bounds__(256)
void gate1_kernel(const float* __restrict__ A,   // w_g1 [128][512]
                  const float* __restrict__ B,   // x [b][512][4096]
                  const float* __restrict__ bias,// b_g1 [128]
                  float* __restrict__ G1)
{
    const int tid = threadIdx.x;
    const int tm = tid & 15;        // m-group (8 rows each)
    const int tn = tid >> 4;        // n-group (2 cols each, 16 groups)
    const int n0 = blockIdx.x * 32;
    const int b  = blockIdx.z;
    const float* Bb = B + (size_t)b * XSTRIDE;

    __shared__ float As[16][132];
    __shared__ float Bs[16][34];

    float acc[8][2];
    #pragma unroll
    for (int i = 0; i < 8; ++i) { acc[i][0] = 0.0f; acc[i][1] = 0.0f; }

    for (int k0 = 0; k0 < 512; k0 += 16) {
        {   // A tile [128 m][16 k]
            int id = tid * 2;
            #pragma unroll
            for (int r = 0; r < 2; ++r, ++id) {
                int m = id >> 2, kq = (id & 3) * 4;
                float4 v = *(const float4*)(A + (size_t)m * 512 + k0 + kq);
                As[kq + 0][m] = v.x; As[kq + 1][m] = v.y;
                As[kq + 2][m] = v.z; As[kq + 3][m] = v.w;
            }
        }
        {   // B tile [16 k][32 n]
            int kk = tid >> 4;            // 0..15
            int nn = (tid & 15) * 2;      // 0..30
            float2 v = *(const float2*)(Bb + (size_t)(k0 + kk) * 4096 + n0 + nn);
            Bs[kk][nn] = v.x; Bs[kk][nn + 1] = v.y;
        }
        __syncthreads();
        #pragma unroll
        for (int k = 0; k < 16; ++k) {
            float4 a0 = *(const float4*)(&As[k][tm * 8]);
            float4 a1 = *(const float4*)(&As[k][tm * 8 + 4]);
            float a[8] = {a0.x, a0.y, a0.z, a0.w, a1.x, a1.y, a1.z, a1.w};
            float b0 = Bs[k][tn * 2], b1 = Bs[k][tn * 2 + 1];
            #pragma unroll
            for (int i = 0; i < 8; ++i) {
                acc[i][0] += a[i] * b0;
                acc[i][1] += a[i] * b1;
            }
        }
        __syncthreads();
    }

    #pragma unroll
    for (int i = 0; i < 8; ++i) {
        int o = tm * 8 + i;
        float bi = bias[o];
        float* dst = G1 + (size_t)b * G1STRIDE + (size_t)o * 4096 + n0 + tn * 2;
        dst[0] = fmaxf(acc[i][0] + bi, 0.0f);
        dst[1] = fmaxf(acc[i][1] + bi, 0.0f);
    }
}

// ---------------------------------------------------------------------------
// R10: convert+transpose x [b][512 k][4096 n] f32 -> XT [b][4096 n][512 k]
// f16 hi + f16 lo*4096 (exact split). XT lives in d_out (16 MB exactly).
// ---------------------------------------------------------------------------
__global__ __launch_bounds__(256)
void convert_kernel(const float* __restrict__ x,
                    f16* __restrict__ XTH, f16* __restrict__ XTL)
{
    __shared__ float T[64][65];
    const int b = blockIdx.z;
    const int n0 = blockIdx.x * 64, k0 = blockIdx.y * 64;
    const int tid = threadIdx.x;
    const float* xb = x + (size_t)b * XSTRIDE;

    {
        const int c = tid & 63, r = tid >> 6;
        #pragma unroll
        for (int i = 0; i < 16; ++i)
            T[r + i * 4][c] = xb[(size_t)(k0 + r + i * 4) * 4096 + n0 + c];
    }
    __syncthreads();
    const int n = tid >> 2, a = tid & 3;   // thread owns one n-row, 16 k vals
    f16x8 vh[2], vl[2];
    #pragma unroll
    for (int p = 0; p < 2; ++p)
        #pragma unroll
        for (int j = 0; j < 8; ++j) {
            float v = T[a * 16 + p * 8 + j][n];
            f16 h = (f16)v;
            vh[p][j] = h;
            vl[p][j] = (f16)((v - (float)h) * 4096.0f);
        }
    size_t dst = ((size_t)(b * 4096) + n0 + n) * 512 + k0 + a * 16;
    *(f16x8*)(XTH + dst)     = vh[0];
    *(f16x8*)(XTH + dst + 8) = vh[1];
    *(f16x8*)(XTL + dst)     = vl[0];
    *(f16x8*)(XTL + dst + 8) = vl[1];
}

// ---------------------------------------------------------------------------
// R10: qkv GEMM on the matrix pipe (3-product hi/lo f16 MFMA; ll dropped).
// Tile 128x128, K-step 16, 4 waves = 2x2 quadrants of 64x64.
// Fragment layout harness-verified: A[m=ln][k=g*8+j], B[n=ln][k=g*8+j],
// C row=(r&3)+8*(r>>2)+4g, col=ln.
// ---------------------------------------------------------------------------
__global__ __launch_bounds__(256, 2)
void qkv_gemm(const float* __restrict__ W, const f16* __restrict__ XTH,
              const f16* __restrict__ XTL,
              f16* __restrict__ QH, f16* __restrict__ QL,
              f16* __restrict__ KH, f16* __restrict__ KL,
              f16* __restrict__ VB)
{
    __shared__ __align__(16) char smem[33792];
    f16* Ah = (f16*)smem;
    f16* Al = (f16*)(smem + 6144);
    f16* Bh = (f16*)(smem + 12288);
    f16* Bl = (f16*)(smem + 18432);

    const int tid  = threadIdx.x;
    const int wid  = tid >> 6, lane = tid & 63;
    const int ln   = lane & 31, g = lane >> 5;
    const int wm   = wid >> 1, wn = wid & 1;
    const int m0   = blockIdx.y * 128;
    const int n0   = blockIdx.x * 128;
    const int b    = blockIdx.z;

    const int sm = tid >> 1, sko = (tid & 1) * 8;    // staging row / k-octet
    const float* wsrc  = W + (size_t)(m0 + sm) * 512 + sko;
    const f16*  bsrcH = XTH + ((size_t)(b * 4096) + n0 + sm) * 512 + sko;
    const f16*  bsrcL = XTL + ((size_t)(b * 4096) + n0 + sm) * 512 + sko;

    f32x16 accH[2][2], accL[2][2];
    #pragma unroll
    for (int rb = 0; rb < 2; ++rb)
        #pragma unroll
        for (int cb = 0; cb < 2; ++cb)
            #pragma unroll
            for (int r = 0; r < 16; ++r) { accH[rb][cb][r] = 0.0f; accL[rb][cb][r] = 0.0f; }

    for (int k0 = 0; k0 < 512; k0 += 16) {
        {   // A stage + hi/lo convert (lo pre-scaled x4096)
            float4 v0 = *(const float4*)(wsrc + k0);
            float4 v1 = *(const float4*)(wsrc + k0 + 4);
            float vv[8] = {v0.x, v0.y, v0.z, v0.w, v1.x, v1.y, v1.z, v1.w};
            f16x8 hh, ll;
            #pragma unroll
            for (int j = 0; j < 8; ++j) {
                f16 h = (f16)vv[j];
                hh[j] = h;
                ll[j] = (f16)((vv[j] - (float)h) * 4096.0f);
            }
            *(f16x8*)(Ah + sm * 24 + sko) = hh;
            *(f16x8*)(Al + sm * 24 + sko) = ll;
            *(f16x8*)(Bh + sm * 24 + sko) = *(const f16x8*)(bsrcH + k0);
            *(f16x8*)(Bl + sm * 24 + sko) = *(const f16x8*)(bsrcL + k0);
        }
        __syncthreads();
        f16x8 a_h[2], a_l[2], b_h[2], b_l[2];
        #pragma unroll
        for (int rb = 0; rb < 2; ++rb) {
            int row = wm * 64 + rb * 32 + ln;
            a_h[rb] = *(const f16x8*)(Ah + row * 24 + g * 8);
            a_l[rb] = *(const f16x8*)(Al + row * 24 + g * 8);
        }
        #pragma unroll
        for (int cb = 0; cb < 2; ++cb) {
            int col = wn * 64 + cb * 32 + ln;
            b_h[cb] = *(const f16x8*)(Bh + col * 24 + g * 8);
            b_l[cb] = *(const f16x8*)(Bl + col * 24 + g * 8);
        }
        #pragma unroll
        for (int rb = 0; rb < 2; ++rb)
            #pragma unroll
            for (int cb = 0; cb < 2; ++cb) {
                accH[rb][cb] = __builtin_amdgcn_mfma_f32_32x32x16_f16(a_h[rb], b_h[cb], accH[rb][cb], 0, 0, 0);
                accL[rb][cb] = __builtin_amdgcn_mfma_f32_32x32x16_f16(a_h[rb], b_l[cb], accL[rb][cb], 0, 0, 0);
                accL[rb][cb] = __builtin_amdgcn_mfma_f32_32x32x16_f16(a_l[rb], b_h[cb], accL[rb][cb], 0, 0, 0);
            }
        __syncthreads();
    }

    // ---- epilogue: per-wave transpose through LDS, then hi/lo split stores
    const int which = m0 >> 9;                       // 0=q 1=k 2=v
    const float scale = (which == 0) ? 0.125f : 1.0f;
    const int hh_ = ((m0 & 511) >> 6) + wm;          // head (block-uniform per wave)
    const size_t rowb0 = (size_t)(b * 8 + hh_) * 4096 + n0 + wn * 64 + lane;
    float* E = (float*)smem + wid * 2112;            // 32 x 66 f32 per wave

    #pragma unroll
    for (int rb = 0; rb < 2; ++rb) {
        #pragma unroll
        for (int cb = 0; cb < 2; ++cb)
            #pragma unroll
            for (int r = 0; r < 16; ++r) {
                int row = (r & 3) + 8 * (r >> 2) + 4 * g;   // verified C mapping
                E[row * 66 + cb * 32 + ln] =
                    accH[rb][cb][r] + accL[rb][cb][r] * (1.0f / 4096.0f);
            }
        __syncthreads();
        const int dbase = rb * 32;
        if (which == 2) {
            #pragma unroll
            for (int oct = 0; oct < 4; ++oct) {
                f16x8 vv;
                #pragma unroll
                for (int j = 0; j < 8; ++j) vv[j] = (f16)E[(oct * 8 + j) * 66 + lane];
                *(f16x8*)(VB + rowb0 * 64 + dbase + oct * 8) = vv;
            }
        } else {
            f16* DH = which ? KH : QH;
            f16* DL = which ? KL : QL;
            #pragma unroll
            for (int oct = 0; oct < 4; ++oct) {
                f16x8 vh, vl;
                #pragma unroll
                for (int j = 0; j < 8; ++j) {
                    float xx = E[(oct * 8 + j) * 66 + lane] * scale;
                    f16 h = (f16)xx;
                    vh[j] = h;
                    vl[j] = (f16)((xx - (float)h) * 4096.0f);
                }
                *(f16x8*)(DH + rowb0 * 64 + dbase + oct * 8) = vh;
                *(f16x8*)(DL + rowb0 * 64 + dbase + oct * 8) = vl;
            }
        }
        __syncthreads();
    }
}

// ---------------------------------------------------------------------------
// R19: proj GEMM on the matrix pipe — mechanical mirror of qkv_gemm.
// A = w_proj (hi/lo in-kernel), B = OH/OL (merge output, [b*4096+n][h*64+d]).
// Epilogue: LDS transpose then coalesced f32 stores of C + bias + resid.
// ---------------------------------------------------------------------------
__global__ __launch_bounds__(256, 2)
void proj_gemm(const float* __restrict__ W, const f16* __restrict__ OH,
               const f16* __restrict__ OL, const float* __restrict__ bias,
               const float* __restrict__ resid, float* __restrict__ out)
{
    __shared__ __align__(16) char smem[33792];
    f16* Ah = (f16*)smem;
    f16* Al = (f16*)(smem + 6144);
    f16* Bh = (f16*)(smem + 12288);
    f16* Bl = (f16*)(smem + 18432);

    const int tid  = threadIdx.x;
    const int wid  = tid >> 6, lane = tid & 63;
    const int ln   = lane & 31, g = lane >> 5;
    const int wm   = wid >> 1, wn = wid & 1;
    const int m0   = blockIdx.y * 128;
    const int n0   = blockIdx.x * 128;
    const int b    = blockIdx.z;

    const int sm = tid >> 1, sko = (tid & 1) * 8;
    const float* wsrc  = W + (size_t)(m0 + sm) * 512 + sko;
    const f16*  bsrcH = OH + ((size_t)(b * 4096) + n0 + sm) * 512 + sko;
    const f16*  bsrcL = OL + ((size_t)(b * 4096) + n0 + sm) * 512 + sko;

    f32x16 accH[2][2], accL[2][2];
    #pragma unroll
    for (int rb = 0; rb < 2; ++rb)
        #pragma unroll
        for (int cb = 0; cb < 2; ++cb)
            #pragma unroll
            for (int r = 0; r < 16; ++r) { accH[rb][cb][r] = 0.0f; accL[rb][cb][r] = 0.0f; }

    for (int k0 = 0; k0 < 512; k0 += 16) {
        {
            float4 v0 = *(const float4*)(wsrc + k0);
            float4 v1 = *(const float4*)(wsrc + k0 + 4);
            float vv[8] = {v0.x, v0.y, v0.z, v0.w, v1.x, v1.y, v1.z, v1.w};
            f16x8 hh, ll;
            #pragma unroll
            for (int j = 0; j < 8; ++j) {
                f16 h = (f16)vv[j];
                hh[j] = h;
                ll[j] = (f16)((vv[j] - (float)h) * 4096.0f);
            }
            *(f16x8*)(Ah + sm * 24 + sko) = hh;
            *(f16x8*)(Al + sm * 24 + sko) = ll;
            *(f16x8*)(Bh + sm * 24 + sko) = *(const f16x8*)(bsrcH + k0);
            *(f16x8*)(Bl + sm * 24 + sko) = *(const f16x8*)(bsrcL + k0);
        }
        __syncthreads();
        f16x8 a_h[2], a_l[2], b_h[2], b_l[2];
        #pragma unroll
        for (int rb = 0; rb < 2; ++rb) {
            int row = wm * 64 + rb * 32 + ln;
            a_h[rb] = *(const f16x8*)(Ah + row * 24 + g * 8);
            a_l[rb] = *(const f16x8*)(Al + row * 24 + g * 8);
        }
        #pragma unroll
        for (int cb = 0; cb < 2; ++cb) {
            int col = wn * 64 + cb * 32 + ln;
            b_h[cb] = *(const f16x8*)(Bh + col * 24 + g * 8);
            b_l[cb] = *(const f16x8*)(Bl + col * 24 + g * 8);
        }
        #pragma unroll
        for (int rb = 0; rb < 2; ++rb)
            #pragma unroll
            for (int cb = 0; cb < 2; ++cb) {
                accH[rb][cb] = __builtin_amdgcn_mfma_f32_32x32x16_f16(a_h[rb], b_h[cb], accH[rb][cb], 0, 0, 0);
                accL[rb][cb] = __builtin_amdgcn_mfma_f32_32x32x16_f16(a_h[rb], b_l[cb], accL[rb][cb], 0, 0, 0);
                accL[rb][cb] = __builtin_amdgcn_mfma_f32_32x32x16_f16(a_l[rb], b_h[cb], accL[rb][cb], 0, 0, 0);
            }
        __syncthreads();
    }

    // ---- epilogue: transpose through LDS, coalesced f32 out += bias+resid
    float* E = (float*)smem + wid * 2112;            // 32 x 66 f32 per wave
    #pragma unroll
    for (int rb = 0; rb < 2; ++rb) {
        #pragma unroll
        for (int cb = 0; cb < 2; ++cb)
            #pragma unroll
            for (int r = 0; r < 16; ++r) {
                int row = (r & 3) + 8 * (r >> 2) + 4 * g;   // verified C mapping
                E[row * 66 + cb * 32 + ln] =
                    accH[rb][cb][r] + accL[rb][cb][r] * (1.0f / 4096.0f);
            }
        __syncthreads();
        #pragma unroll 4
        for (int r = 0; r < 32; ++r) {
            int o = m0 + wm * 64 + rb * 32 + r;
            size_t off = (size_t)b * XSTRIDE + (size_t)o * 4096
                       + n0 + wn * 64 + lane;
            out[off] = E[r * 66 + lane] + bias[o] + resid[off];
        }
        __syncthreads();
    }
}

// ---------------------------------------------------------------------------
// gate2 (exact fp32 path — trunc(tau*32) is discrete, do not perturb).
// ---------------------------------------------------------------------------
__global__ __launch_bounds__(64)
void gate2_kernel(const float* __restrict__ G1, const float* __restrict__ w2,
                  const float* __restrict__ b2, int* __restrict__ KD)
{
    const int b = blockIdx.y;
    const int n = blockIdx.x * 64 + threadIdx.x;
    const float* g = G1 + (size_t)b * G1STRIDE + n;
    float z = b2[0];
    #pragma unroll 8
    for (int c = 0; c < 128; ++c) z += w2[c] * g[(size_t)c * 4096];
    float tau = 1.0f / (1.0f + expf(-z));
    int kd = (int)(tau * 32.0f);
    kd = min(32, max(4, kd));
    KD[b * 4096 + n] = kd;
}

// ---------------------------------------------------------------------------
// R20 select: 2-wave key-quarter split for occupancy.
// R14's structure had 2048 one-wave blocks = 2 waves/SIMD (grid-pinned 21%
// occupancy; VALUBusy 49% = half the wall is latency stall). R16 failed by
// halving per-PHASE work (latency-bound); R20 instead halves PHASES per wave:
// each block has 2 waves over the SAME 64 rows, each wave owning one key
// QUARTER (1024 keys = 16 t-blocks) with the full 64x32 phase shape. Waves
// double -> 4/SIMD. Chip-wide ladder work rises ~1.7x, absorbed by idle
// VALU issue slots.
// Exactness: per-wave pass 1 gives exact quarter top-32 (values). Cross-wave
// merge via LDS: Batcher halver M[i]=max(A[i],B[31-i]) + bitonic clean,
// in-place over L with B streamed from LDS (no extra register arrays) ->
// exact half top-32 -> theta identical to R14's. Tie bookkeeping computed
// deterministically by BOTH waves from the two LDS lists (gtA/gtB/eqA/A31):
// quarter-A (smaller j) captures its eq's first; slot order = A then B =
// global j-ascending == R14's order. CV/CI bytes identical to R14 ->
// absmax must be exactly 0.08642578.
// Machinery notes (hard-won): scans are _Pragma MACROS (lambdas alloca'd
// L[32] into LDS in R12); K-frag dbuf as NAMED f16x8 vars; no scan prefetch
// (R15 null). waves_per_eu(3,4): allocator <=170 regs, 4 waves if <=128.
// ---------------------------------------------------------------------------
#define LOAD_BF(B0,B1,B2,B3,B4,B5,B6,B7, KHP, KLP, CB) do {                   \
    const f16* _ph = (KHP) + (size_t)((CB) * 32 + ln) * 64 + g * 8;           \
    const f16* _pl = (KLP) + (size_t)((CB) * 32 + ln) * 64 + g * 8;           \
    B0 = *(const f16x8*)(_ph);      B1 = *(const f16x8*)(_ph + 16);           \
    B2 = *(const f16x8*)(_ph + 32); B3 = *(const f16x8*)(_ph + 48);           \
    B4 = *(const f16x8*)(_pl);      B5 = *(const f16x8*)(_pl + 16);           \
    B6 = *(const f16x8*)(_pl + 32); B7 = *(const f16x8*)(_pl + 48);           \
} while (0)

// pass-1 scan of Ss: med3 ladder + lagged thr refresh (expects srow, thr,
// L[], kdm1 in scope)
#define P1_SCAN() do {                                                        \
    u32 _m = 0;                                                               \
    _Pragma("unroll")                                                         \
    for (int _q = 0; _q < 16; ++_q) {                                         \
        float2 _v = *(const float2*)(srow + 2 * _q);                          \
        _m |= (_v.x > thr) ? (1u << (2 * _q)) : 0u;                           \
        _m |= (_v.y > thr) ? (1u << (2 * _q + 1)) : 0u;                       \
    }                                                                         \
    while (__ballot(_m != 0u)) {                                              \
        bool _act = (_m != 0u);                                               \
        int _j = __builtin_ctz(_m ? _m : 1u);                                 \
        float _c = _act ? srow[_j] : 0.0f;                                    \
        _m &= (_m - 1u);                                                      \
        if (_act && _c > thr) {                                               \
            _Pragma("unroll")                                                 \
            for (int _r = 31; _r >= 1; --_r)                                  \
                L[_r] = __builtin_amdgcn_fmed3f(_c, L[_r - 1], L[_r]);        \
            L[0] = fmaxf(L[0], _c);                                           \
        }                                                                     \
    }                                                                         \
    {                                                                         \
        float _th = L[31];                                                    \
        _Pragma("unroll")                                                     \
        for (int _r = 30; _r >= 0; --_r) _th = (kdm1 == _r) ? L[_r] : _th;    \
        thr = _th;                                                            \
    }                                                                         \
} while (0)

// pass-2 scan with per-wave slot base and caps (expects srow, theta,
// eqNeedW, capW, slotBase, cnt, eqc, cvp, cip in scope)
#define P2_SCANQ(JBASE) do {                                                  \
    u32 _m = 0;                                                               \
    _Pragma("unroll")                                                         \
    for (int _q = 0; _q < 16; ++_q) {                                         \
        float2 _v = *(const float2*)(srow + 2 * _q);                          \
        _m |= (_v.x >= theta) ? (1u << (2 * _q)) : 0u;                        \
        _m |= (_v.y >= theta) ? (1u << (2 * _q + 1)) : 0u;                    \
    }                                                                         \
    while (__ballot(_m != 0u)) {                                              \
        bool _act = (_m != 0u);                                               \
        int _j = __builtin_ctz(_m ? _m : 1u);                                 \
        float _c = _act ? srow[_j] : 0.0f;                                    \
        _m &= (_m - 1u);                                                      \
        if (_act) {                                                           \
            bool _isGT = _c > theta;                                          \
            bool _doA = (_isGT || eqc < eqNeedW) && cnt < capW;               \
            if (_doA) {                                                       \
                cvp[slotBase + cnt] = _c;                                     \
                cip[slotBase + cnt] = (u16)((JBASE) + _j);                    \
                cnt++;                                                        \
                if (!_isGT) eqc++;                                            \
            }                                                                 \
        }                                                                     \
    }                                                                         \
} while (0)

__device__ __forceinline__ void score_from(
    f16x8 bh0, f16x8 bh1, f16x8 bh2, f16x8 bh3,
    f16x8 bl0, f16x8 bl1, f16x8 bl2, f16x8 bl3,
    const f16x8 ah[2][4], const f16x8 al[2][4],
    float* __restrict__ Ss, int ln, int g)
{
    __builtin_amdgcn_s_setprio(1);
    #pragma unroll
    for (int rb = 0; rb < 2; ++rb) {
        f32x16 acc, accL;
        #pragma unroll
        for (int r = 0; r < 16; ++r) { acc[r] = 0.0f; accL[r] = 0.0f; }
        // s-order and per-s op order verbatim R11: hh, lh, hl
        acc  = __builtin_amdgcn_mfma_f32_32x32x16_f16(ah[rb][0], bh0, acc,  0, 0, 0);
        accL = __builtin_amdgcn_mfma_f32_32x32x16_f16(al[rb][0], bh0, accL, 0, 0, 0);
        accL = __builtin_amdgcn_mfma_f32_32x32x16_f16(ah[rb][0], bl0, accL, 0, 0, 0);
        acc  = __builtin_amdgcn_mfma_f32_32x32x16_f16(ah[rb][1], bh1, acc,  0, 0, 0);
        accL = __builtin_amdgcn_mfma_f32_32x32x16_f16(al[rb][1], bh1, accL, 0, 0, 0);
        accL = __builtin_amdgcn_mfma_f32_32x32x16_f16(ah[rb][1], bl1, accL, 0, 0, 0);
        acc  = __builtin_amdgcn_mfma_f32_32x32x16_f16(ah[rb][2], bh2, acc,  0, 0, 0);
        accL = __builtin_amdgcn_mfma_f32_32x32x16_f16(al[rb][2], bh2, accL, 0, 0, 0);
        accL = __builtin_amdgcn_mfma_f32_32x32x16_f16(ah[rb][2], bl2, accL, 0, 0, 0);
        acc  = __builtin_amdgcn_mfma_f32_32x32x16_f16(ah[rb][3], bh3, acc,  0, 0, 0);
        accL = __builtin_amdgcn_mfma_f32_32x32x16_f16(al[rb][3], bh3, accL, 0, 0, 0);
        accL = __builtin_amdgcn_mfma_f32_32x32x16_f16(ah[rb][3], bl3, accL, 0, 0, 0);
        // C layout: row=(r&3)+8*(r>>2)+4g, col=ln (verified m74/m101)
        #pragma unroll
        for (int r = 0; r < 16; ++r) {
            int riw = rb * 32 + (r & 3) + 8 * (r >> 2) + 4 * g;
            Ss[riw * 34 + ln] = acc[r] + accL[r] * (1.0f / 4096.0f);
        }
    }
    __builtin_amdgcn_s_setprio(0);
}

// ---------------------------------------------------------------------------
// select v10 (R20): 2 waves/block over key quarters. Grid (128,8,2) x 128thr.
// ---------------------------------------------------------------------------
__global__ __launch_bounds__(128)
__attribute__((amdgpu_waves_per_eu(3, 4)))
void select_kernel(const f16* __restrict__ QH, const f16* __restrict__ QL,
                   const f16* __restrict__ KH, const f16* __restrict__ KL,
                   const int* __restrict__ KD,
                   float* __restrict__ CV, u16* __restrict__ CI)
{
    const int qt = blockIdx.x >> 1;     // 64-row group
    const int hf = blockIdx.x & 1;      // key half
    const int h = blockIdx.y, b = blockIdx.z;
    const size_t base = (size_t)((b * 8 + h) * 4096) * 64;
    const int tid = threadIdx.x;
    const int wv = tid >> 6;            // wave: 0 = quarter A, 1 = quarter B
    const int lane = tid & 63;
    const int ln = lane & 31, g = lane >> 5;
    const int nw = qt * 64;
    const int k0base = hf * 2048 + wv * 1024;   // own quarter's key base

    const int kd = KD[b * 4096 + nw + lane];    // same per row for both waves
    const int kdm1 = kd - 1;

    __shared__ float Ss2[2][64 * 34];   // per-wave score slab / list overlay
    float* Ss = Ss2[wv];
    const float* srow = &Ss[lane * 34];

    // resident Q frags: A[m=ln][k=16s+8g+j] (rows identical for both waves)
    f16x8 ah[2][4], al[2][4];
    #pragma unroll
    for (int rb = 0; rb < 2; ++rb) {
        const f16* ph = QH + base + (size_t)(nw + rb * 32 + ln) * 64 + g * 8;
        const f16* pl = QL + base + (size_t)(nw + rb * 32 + ln) * 64 + g * 8;
        #pragma unroll
        for (int s = 0; s < 4; ++s) {
            ah[rb][s] = *(const f16x8*)(ph + s * 16);
            al[rb][s] = *(const f16x8*)(pl + s * 16);
        }
    }

    const float INF = __builtin_inff();

    // named-register double buffer (NO struct/array -> stays in VGPRs)
    f16x8 c0, c1, c2, c3, c4, c5, c6, c7;
    f16x8 n0, n1, n2, n3, n4, n5, n6, n7;

    // ============ pass 1: per-quarter values-only top-32 ============
    float L[32];
    #pragma unroll
    for (int r = 0; r < 32; ++r) L[r] = -INF;
    float thr = -INF;                    // lagged L[kd-1] (refreshed per block)

    {
        const f16* khQ = KH + base + (size_t)k0base * 64;
        const f16* klQ = KL + base + (size_t)k0base * 64;
        LOAD_BF(c0, c1, c2, c3, c4, c5, c6, c7, khQ, klQ, 0);
        for (int t = 0; t < 16; ++t) {
            const f16* kh_t = khQ + (size_t)(t * 64) * 64;
            const f16* kl_t = klQ + (size_t)(t * 64) * 64;
            const int t1 = (t < 15) ? t + 1 : 15;
            const f16* kh_n = khQ + (size_t)(t1 * 64) * 64;
            const f16* kl_n = klQ + (size_t)(t1 * 64) * 64;
            LOAD_BF(n0, n1, n2, n3, n4, n5, n6, n7, kh_t, kl_t, 1);
            score_from(c0, c1, c2, c3, c4, c5, c6, c7, ah, al, Ss, ln, g);
            P1_SCAN();
            LOAD_BF(c0, c1, c2, c3, c4, c5, c6, c7, kh_n, kl_n, 0);
            score_from(n0, n1, n2, n3, n4, n5, n6, n7, ah, al, Ss, ln, g);
            P1_SCAN();
        }
    }

    // ============ cross-wave merge: exact half top-32 ============
    // park own sorted list (stride 33, conflict-free walk) in own Ss region
    #pragma unroll
    for (int r = 0; r < 32; ++r) Ss[lane * 33 + r] = L[r];
    __syncthreads();
    {
        // Batcher halver into L in place, other's list streamed from LDS:
        // L[i] = max(own[i], other[31-i]) is the top-32 multiset (bitonic)
        const float* oth = &Ss2[wv ^ 1][0];
        #pragma unroll
        for (int i = 0; i < 32; ++i)
            L[i] = fmaxf(L[i], oth[lane * 33 + (31 - i)]);
        // bitonic clean -> sorted descending
        #pragma unroll
        for (int d = 16; d >= 1; d >>= 1)
            #pragma unroll
            for (int i = 0; i < 32; ++i)
                if (!(i & d) && (i + d) < 32) {
                    float a_ = L[i], b_ = L[i + d];
                    L[i] = fmaxf(a_, b_);
                    L[i + d] = fminf(a_, b_);
                }
    }
    float theta;                         // exact kd-th largest of the half
    {
        float th = L[31];
        #pragma unroll
        for (int r = 30; r >= 0; --r) th = (kdm1 == r) ? L[r] : th;
        theta = th;
    }
    // tie bookkeeping from the two parked lists (registers now hold merged M)
    int gtA = 0, eqA = 0, gtB = 0;
    float A31;
    {
        const float* la = &Ss2[0][0];
        const float* lb = &Ss2[1][0];
        #pragma unroll
        for (int r = 0; r < 32; ++r) {
            float av = la[lane * 33 + r];
            float bv = lb[lane * 33 + r];
            gtA += (av > theta) ? 1 : 0;
            eqA += (av == theta) ? 1 : 0;
            gtB += (bv > theta) ? 1 : 0;
        }
        A31 = la[lane * 33 + 31];
    }
    __syncthreads();                     // lists consumed; Ss free for pass 2

    // quarter-A eq's (smaller j) take precedence; A[31]==theta edge means
    // quarter A alone supplies >= eqNeed in-list equals (proof in notes).
    const int eqNeed = kd - gtA - gtB;
    const int eqCapA = (A31 == theta) ? eqNeed : min(eqA, eqNeed);
    const int capA   = gtA + eqCapA;
    const int slotBase = wv ? capA : 0;
    const int capW     = wv ? (kd - capA) : capA;
    const int eqNeedW  = wv ? (eqNeed - eqCapA) : eqCapA;

    // ============ pass 2: capture indices over own quarter ============
    const size_t crow = (size_t)((b * 8 + h) * 4096 + nw + lane);
    float* cvp = CV + crow * 64 + hf * 32;
    u16*   cip = CI + crow * 64 + hf * 32;
    int cnt = 0, eqc = 0;

    {
        const f16* khQ = KH + base + (size_t)k0base * 64;
        const f16* klQ = KL + base + (size_t)k0base * 64;
        LOAD_BF(c0, c1, c2, c3, c4, c5, c6, c7, khQ, klQ, 0);
        for (int t = 0; t < 16; ++t) {
            const f16* kh_t = khQ + (size_t)(t * 64) * 64;
            const f16* kl_t = klQ + (size_t)(t * 64) * 64;
            const int t1 = (t < 15) ? t + 1 : 15;
            const f16* kh_n = khQ + (size_t)(t1 * 64) * 64;
            const f16* kl_n = klQ + (size_t)(t1 * 64) * 64;
            LOAD_BF(n0, n1, n2, n3, n4, n5, n6, n7, kh_t, kl_t, 1);
            score_from(c0, c1, c2, c3, c4, c5, c6, c7, ah, al, Ss, ln, g);
            P2_SCANQ(k0base + t * 64);
            LOAD_BF(c0, c1, c2, c3, c4, c5, c6, c7, kh_n, kl_n, 0);
            score_from(n0, n1, n2, n3, n4, n5, n6, n7, ah, al, Ss, ln, g);
            P2_SCANQ(k0base + t * 64 + 32);
        }
    }
}

// ---------------------------------------------------------------------------
// merge v3 (R19): sort-insert + softmax + V gather; O emitted as f16 hi/lo
// (OH/OL) in proj's B-operand layout [b*4096+n][c=h*64+d].
// ---------------------------------------------------------------------------
__global__ __launch_bounds__(64)
void merge_kernel(const float* __restrict__ CV, const u16* __restrict__ CI,
                  const int* __restrict__ KD, const f16* __restrict__ VB,
                  f16* __restrict__ OH, f16* __restrict__ OL)
{
    const int tid = threadIdx.x;
    const size_t R0 = (size_t)blockIdx.x * 64;

    __shared__ float Lv[64][66];
    __shared__ u16   Li[64][66];
    __shared__ float Mv[64][34];
    __shared__ u16   Mi[64][34];

    for (int i = 0; i < 64; ++i) {       // coalesced stage
        Lv[i][tid] = CV[(R0 + i) * 64 + tid];
        Li[i][tid] = CI[(R0 + i) * 64 + tid];
    }
    __syncthreads();

    const int myR = (int)R0 + tid;       // = (b*8+h)*4096 + n
    const int b = myR >> 15, n = myR & 4095, h = (myR >> 12) & 7;
    const int kd = KD[b * 4096 + n];

    const float INF = __builtin_inff();
    float L[32]; int I[32];
    #pragma unroll
    for (int r = 0; r < 32; ++r) { L[r] = -INF; I[r] = 0; }

    for (int i = 0; i < 64; ++i) {
        float c = Lv[tid][i];            // NaN filler: all compares false
        int  ix = Li[tid][i];
        if (c > L[31]) {
            #pragma unroll
            for (int r = 31; r >= 1; --r) {
                bool gp = c > L[r - 1];
                bool gc = c > L[r];
                L[r] = gp ? L[r - 1] : (gc ? c : L[r]);
                I[r] = gp ? I[r - 1] : (gc ? ix : I[r]);
            }
            if (c > L[0]) { I[0] = ix; L[0] = c; }
        }
    }

    // park sorted list (register->LDS) for dynamic-index softmax/gather
    #pragma unroll
    for (int r = 0; r < 32; ++r) { Mv[tid][r] = L[r]; Mi[tid][r] = (u16)I[r]; }

    const float mx = Mv[tid][0];
    float sum = 0.0f;
    for (int k = 0; k < kd; ++k) {       // rank order, matches reference
        float e = expf(Mv[tid][k] - mx);
        Mv[tid][k] = e;
        sum += e;
    }
    const float inv = 1.0f / sum;

    float o[64];
    #pragma unroll
    for (int d = 0; d < 64; ++d) o[d] = 0.0f;
    const size_t vbase = (size_t)((b * 8 + h)) * 4096 * 64;
    for (int k = 0; k < kd; ++k) {
        float wgt = Mv[tid][k] * inv;
        const f16* vp = VB + vbase + (size_t)Mi[tid][k] * 64;
        #pragma unroll
        for (int part = 0; part < 8; ++part) {
            f16x8 vv = *(const f16x8*)(vp + part * 8);
            #pragma unroll
            for (int e2 = 0; e2 < 8; ++e2) o[part * 8 + e2] += wgt * (float)vv[e2];
        }
    }

    // hi/lo split store in proj's B layout: [b*4096+n][h*64+d]
    const size_t obase = ((size_t)(b * 4096) + n) * 512 + h * 64;
    #pragma unroll
    for (int part = 0; part < 8; ++part) {
        f16x8 vh, vl;
        #pragma unroll
        for (int e2 = 0; e2 < 8; ++e2) {
            float v = o[part * 8 + e2];
            f16 hh = (f16)v;
            vh[e2] = hh;
            vl[e2] = (f16)((v - (float)hh) * 4096.0f);
        }
        *(f16x8*)(OH + obase + part * 8) = vh;
        *(f16x8*)(OL + obase + part * 8) = vl;
    }
}

// ---------------------------------------------------------------------------
extern "C" void kernel_launch(void* const* d_in, const int* in_sizes, int n_in,
                              void* d_out, int out_size, void* d_ws, size_t ws_size,
                              hipStream_t stream)
{
    const float* x      = (const float*)d_in[0];
    const float* w_qkv  = (const float*)d_in[1];
    const float* w_proj = (const float*)d_in[2];
    const float* b_proj = (const float*)d_in[3];
    const float* w_g1   = (const float*)d_in[4];
    const float* b_g1   = (const float*)d_in[5];
    const float* w_g2   = (const float*)d_in[6];
    const float* b_g2   = (const float*)d_in[7];
    float* out = (float*)d_out;
    float* ws  = (float*)d_ws;

    f16* QH = (f16*)(ws + WS_QH);
    f16* QL = (f16*)(ws + WS_QL);
    f16* KH = (f16*)(ws + WS_KH);
    f16* KL = (f16*)(ws + WS_KL);
    f16* VB = (f16*)(ws + WS_VB);
    float* G1 = ws + WS_G1;
    int*   KD = (int*)(ws + WS_KD);
    u16*   CI = (u16*)(ws + WS_CI);
    float* CV = out;          // d_out as CV scratch (NaN-filled; proj overwrites later)
    f16* OH = (f16*)QH;       // overlay: O (f16 hi/lo) replaces Q hi/lo
    f16* OL = (f16*)QL;

    // d_out first hosts XT (x transposed, f16 hi/lo) for the MFMA qkv GEMM;
    // the NaN memset (CV claim) runs AFTER the consumers.
    f16* XTH = (f16*)out;
    f16* XTL = (f16*)out + 4194304;   // +8 MB (4M f16)

    convert_kernel<<<dim3(64, 8, 2), 256, 0, stream>>>(x, XTH, XTL);
    qkv_gemm<<<dim3(32, 12, 2), 256, 0, stream>>>(
        w_qkv, XTH, XTL, QH, QL, KH, KL, VB);
    gate1_kernel<<<dim3(128, 1, 2), 256, 0, stream>>>(w_g1, x, b_g1, G1);

    // CV = NaN filler (0xFF bytes): unwritten slots never insert in merge
    hipMemsetAsync(CV, 0xFF, (size_t)out_size * sizeof(float), stream);

    gate2_kernel<<<dim3(64, 2), 64, 0, stream>>>(G1, w_g2, b_g2, KD);
    select_kernel<<<dim3(128, 8, 2), 128, 0, stream>>>(QH, QL, KH, KL, KD, CV, CI);
    merge_kernel<<<dim3(1024), 64, 0, stream>>>(CV, CI, KD, VB, OH, OL);
    proj_gemm<<<dim3(32, 4, 2), 256, 0, stream>>>(
        w_proj, OH, OL, b_proj, x, out);
}

// Round 12
// 882.499 us; speedup vs baseline: 1.2703x; 1.2703x over previous
//
#include <hip/hip_runtime.h>
#include <math.h>

// Problem constants: B=2, C=512, H=8 heads, dh=64, N=4096, Kmax=32
#define XSTRIDE  2097152u  // 512*4096 per-batch stride of x / out
#define G1STRIDE 524288u   // 128*4096

typedef _Float16 f16;
typedef f16   f16x8  __attribute__((ext_vector_type(8)));
typedef float f32x16 __attribute__((ext_vector_type(16)));
typedef unsigned int u32;
typedef unsigned short u16;

// ws layout (float offsets). Total 13,639,680 floats = 54.56 MB.
// CV lives in d_out: memset NaN -> select writes -> merge reads -> proj
// overwrites d_out. d_out also hosts XTH/XTL (16 MB) BEFORE the memset.
// merge emits OH/OL (f16 hi/lo, [b*4096+n][c=h*64+d]) overlaid on QH/QL
// (Q dead after select); proj_gemm consumes them on the matrix pipe.
#define WS_QH 0u          // f16 [2][8][4096][64]; later OH f16 [8192][512]
#define WS_QL 2097152u    // f16 lo parts; later OL
#define WS_KH 4194304u
#define WS_KL 6291456u
#define WS_VB 8388608u    // f16 V
#define WS_G1 10485760u   // f32 [2][128][4096]
#define WS_KD 11534336u   // int [2][4096]
#define WS_CI 11542528u   // u16 [65536 rows][64 slots]

// ---------------------------------------------------------------------------
// R17: gate1 GEMM with 128x32 N-tiles -> grid (128,1,2) = 256 blocks = 1/CU.
// Accumulation chain identical to the original -> G1 bitwise-identical.
// ---------------------------------------------------------------------------
__global__ __launch_bounds__(256)
void gate1_kernel(const float* __restrict__ A,   // w_g1 [128][512]
                  const float* __restrict__ B,   // x [b][512][4096]
                  const float* __restrict__ bias,// b_g1 [128]
                  float* __restrict__ G1)
{
    const int tid = threadIdx.x;
    const int tm = tid & 15;        // m-group (8 rows each)
    const int tn = tid >> 4;        // n-group (2 cols each, 16 groups)
    const int n0 = blockIdx.x * 32;
    const int b  = blockIdx.z;
    const float* Bb = B + (size_t)b * XSTRIDE;

    __shared__ float As[16][132];
    __shared__ float Bs[16][34];

    float acc[8][2];
    #pragma unroll
    for (int i = 0; i < 8; ++i) { acc[i][0] = 0.0f; acc[i][1] = 0.0f; }

    for (int k0 = 0; k0 < 512; k0 += 16) {
        {   // A tile [128 m][16 k]
            int id = tid * 2;
            #pragma unroll
            for (int r = 0; r < 2; ++r, ++id) {
                int m = id >> 2, kq = (id & 3) * 4;
                float4 v = *(const float4*)(A + (size_t)m * 512 + k0 + kq);
                As[kq + 0][m] = v.x; As[kq + 1][m] = v.y;
                As[kq + 2][m] = v.z; As[kq + 3][m] = v.w;
            }
        }
        {   // B tile [16 k][32 n]
            int kk = tid >> 4;            // 0..15
            int nn = (tid & 15) * 2;      // 0..30
            float2 v = *(const float2*)(Bb + (size_t)(k0 + kk) * 4096 + n0 + nn);
            Bs[kk][nn] = v.x; Bs[kk][nn + 1] = v.y;
        }
        __syncthreads();
        #pragma unroll
        for (int k = 0; k < 16; ++k) {
            float4 a0 = *(const float4*)(&As[k][tm * 8]);
            float4 a1 = *(const float4*)(&As[k][tm * 8 + 4]);
            float a[8] = {a0.x, a0.y, a0.z, a0.w, a1.x, a1.y, a1.z, a1.w};
            float b0 = Bs[k][tn * 2], b1 = Bs[k][tn * 2 + 1];
            #pragma unroll
            for (int i = 0; i < 8; ++i) {
                acc[i][0] += a[i] * b0;
                acc[i][1] += a[i] * b1;
            }
        }
        __syncthreads();
    }

    #pragma unroll
    for (int i = 0; i < 8; ++i) {
        int o = tm * 8 + i;
        float bi = bias[o];
        float* dst = G1 + (size_t)b * G1STRIDE + (size_t)o * 4096 + n0 + tn * 2;
        dst[0] = fmaxf(acc[i][0] + bi, 0.0f);
        dst[1] = fmaxf(acc[i][1] + bi, 0.0f);
    }
}

// ---------------------------------------------------------------------------
// R10: convert+transpose x [b][512 k][4096 n] f32 -> XT [b][4096 n][512 k]
// f16 hi + f16 lo*4096 (exact split). XT lives in d_out (16 MB exactly).
// ---------------------------------------------------------------------------
__global__ __launch_bounds__(256)
void convert_kernel(const float* __restrict__ x,
                    f16* __restrict__ XTH, f16* __restrict__ XTL)
{
    __shared__ float T[64][65];
    const int b = blockIdx.z;
    const int n0 = blockIdx.x * 64, k0 = blockIdx.y * 64;
    const int tid = threadIdx.x;
    const float* xb = x + (size_t)b * XSTRIDE;

    {
        const int c = tid & 63, r = tid >> 6;
        #pragma unroll
        for (int i = 0; i < 16; ++i)
            T[r + i * 4][c] = xb[(size_t)(k0 + r + i * 4) * 4096 + n0 + c];
    }
    __syncthreads();
    const int n = tid >> 2, a = tid & 3;   // thread owns one n-row, 16 k vals
    f16x8 vh[2], vl[2];
    #pragma unroll
    for (int p = 0; p < 2; ++p)
        #pragma unroll
        for (int j = 0; j < 8; ++j) {
            float v = T[a * 16 + p * 8 + j][n];
            f16 h = (f16)v;
            vh[p][j] = h;
            vl[p][j] = (f16)((v - (float)h) * 4096.0f);
        }
    size_t dst = ((size_t)(b * 4096) + n0 + n) * 512 + k0 + a * 16;
    *(f16x8*)(XTH + dst)     = vh[0];
    *(f16x8*)(XTH + dst + 8) = vh[1];
    *(f16x8*)(XTL + dst)     = vl[0];
    *(f16x8*)(XTL + dst + 8) = vl[1];
}

// ---------------------------------------------------------------------------
// R10: qkv GEMM on the matrix pipe (3-product hi/lo f16 MFMA; ll dropped).
// Tile 128x128, K-step 16, 4 waves = 2x2 quadrants of 64x64.
// Fragment layout harness-verified: A[m=ln][k=g*8+j], B[n=ln][k=g*8+j],
// C row=(r&3)+8*(r>>2)+4g, col=ln.
// ---------------------------------------------------------------------------
__global__ __launch_bounds__(256, 2)
void qkv_gemm(const float* __restrict__ W, const f16* __restrict__ XTH,
              const f16* __restrict__ XTL,
              f16* __restrict__ QH, f16* __restrict__ QL,
              f16* __restrict__ KH, f16* __restrict__ KL,
              f16* __restrict__ VB)
{
    __shared__ __align__(16) char smem[33792];
    f16* Ah = (f16*)smem;
    f16* Al = (f16*)(smem + 6144);
    f16* Bh = (f16*)(smem + 12288);
    f16* Bl = (f16*)(smem + 18432);

    const int tid  = threadIdx.x;
    const int wid  = tid >> 6, lane = tid & 63;
    const int ln   = lane & 31, g = lane >> 5;
    const int wm   = wid >> 1, wn = wid & 1;
    const int m0   = blockIdx.y * 128;
    const int n0   = blockIdx.x * 128;
    const int b    = blockIdx.z;

    const int sm = tid >> 1, sko = (tid & 1) * 8;    // staging row / k-octet
    const float* wsrc  = W + (size_t)(m0 + sm) * 512 + sko;
    const f16*  bsrcH = XTH + ((size_t)(b * 4096) + n0 + sm) * 512 + sko;
    const f16*  bsrcL = XTL + ((size_t)(b * 4096) + n0 + sm) * 512 + sko;

    f32x16 accH[2][2], accL[2][2];
    #pragma unroll
    for (int rb = 0; rb < 2; ++rb)
        #pragma unroll
        for (int cb = 0; cb < 2; ++cb)
            #pragma unroll
            for (int r = 0; r < 16; ++r) { accH[rb][cb][r] = 0.0f; accL[rb][cb][r] = 0.0f; }

    for (int k0 = 0; k0 < 512; k0 += 16) {
        {   // A stage + hi/lo convert (lo pre-scaled x4096)
            float4 v0 = *(const float4*)(wsrc + k0);
            float4 v1 = *(const float4*)(wsrc + k0 + 4);
            float vv[8] = {v0.x, v0.y, v0.z, v0.w, v1.x, v1.y, v1.z, v1.w};
            f16x8 hh, ll;
            #pragma unroll
            for (int j = 0; j < 8; ++j) {
                f16 h = (f16)vv[j];
                hh[j] = h;
                ll[j] = (f16)((vv[j] - (float)h) * 4096.0f);
            }
            *(f16x8*)(Ah + sm * 24 + sko) = hh;
            *(f16x8*)(Al + sm * 24 + sko) = ll;
            *(f16x8*)(Bh + sm * 24 + sko) = *(const f16x8*)(bsrcH + k0);
            *(f16x8*)(Bl + sm * 24 + sko) = *(const f16x8*)(bsrcL + k0);
        }
        __syncthreads();
        f16x8 a_h[2], a_l[2], b_h[2], b_l[2];
        #pragma unroll
        for (int rb = 0; rb < 2; ++rb) {
            int row = wm * 64 + rb * 32 + ln;
            a_h[rb] = *(const f16x8*)(Ah + row * 24 + g * 8);
            a_l[rb] = *(const f16x8*)(Al + row * 24 + g * 8);
        }
        #pragma unroll
        for (int cb = 0; cb < 2; ++cb) {
            int col = wn * 64 + cb * 32 + ln;
            b_h[cb] = *(const f16x8*)(Bh + col * 24 + g * 8);
            b_l[cb] = *(const f16x8*)(Bl + col * 24 + g * 8);
        }
        #pragma unroll
        for (int rb = 0; rb < 2; ++rb)
            #pragma unroll
            for (int cb = 0; cb < 2; ++cb) {
                accH[rb][cb] = __builtin_amdgcn_mfma_f32_32x32x16_f16(a_h[rb], b_h[cb], accH[rb][cb], 0, 0, 0);
                accL[rb][cb] = __builtin_amdgcn_mfma_f32_32x32x16_f16(a_h[rb], b_l[cb], accL[rb][cb], 0, 0, 0);
                accL[rb][cb] = __builtin_amdgcn_mfma_f32_32x32x16_f16(a_l[rb], b_h[cb], accL[rb][cb], 0, 0, 0);
            }
        __syncthreads();
    }

    // ---- epilogue: per-wave transpose through LDS, then hi/lo split stores
    const int which = m0 >> 9;                       // 0=q 1=k 2=v
    const float scale = (which == 0) ? 0.125f : 1.0f;
    const int hh_ = ((m0 & 511) >> 6) + wm;          // head (block-uniform per wave)
    const size_t rowb0 = (size_t)(b * 8 + hh_) * 4096 + n0 + wn * 64 + lane;
    float* E = (float*)smem + wid * 2112;            // 32 x 66 f32 per wave

    #pragma unroll
    for (int rb = 0; rb < 2; ++rb) {
        #pragma unroll
        for (int cb = 0; cb < 2; ++cb)
            #pragma unroll
            for (int r = 0; r < 16; ++r) {
                int row = (r & 3) + 8 * (r >> 2) + 4 * g;   // verified C mapping
                E[row * 66 + cb * 32 + ln] =
                    accH[rb][cb][r] + accL[rb][cb][r] * (1.0f / 4096.0f);
            }
        __syncthreads();
        const int dbase = rb * 32;
        if (which == 2) {
            #pragma unroll
            for (int oct = 0; oct < 4; ++oct) {
                f16x8 vv;
                #pragma unroll
                for (int j = 0; j < 8; ++j) vv[j] = (f16)E[(oct * 8 + j) * 66 + lane];
                *(f16x8*)(VB + rowb0 * 64 + dbase + oct * 8) = vv;
            }
        } else {
            f16* DH = which ? KH : QH;
            f16* DL = which ? KL : QL;
            #pragma unroll
            for (int oct = 0; oct < 4; ++oct) {
                f16x8 vh, vl;
                #pragma unroll
                for (int j = 0; j < 8; ++j) {
                    float xx = E[(oct * 8 + j) * 66 + lane] * scale;
                    f16 h = (f16)xx;
                    vh[j] = h;
                    vl[j] = (f16)((xx - (float)h) * 4096.0f);
                }
                *(f16x8*)(DH + rowb0 * 64 + dbase + oct * 8) = vh;
                *(f16x8*)(DL + rowb0 * 64 + dbase + oct * 8) = vl;
            }
        }
        __syncthreads();
    }
}

// ---------------------------------------------------------------------------
// R19: proj GEMM on the matrix pipe — mechanical mirror of qkv_gemm.
// A = w_proj (hi/lo in-kernel), B = OH/OL (merge output, [b*4096+n][h*64+d]).
// Epilogue: LDS transpose then coalesced f32 stores of C + bias + resid.
// ---------------------------------------------------------------------------
__global__ __launch_bounds__(256, 2)
void proj_gemm(const float* __restrict__ W, const f16* __restrict__ OH,
               const f16* __restrict__ OL, const float* __restrict__ bias,
               const float* __restrict__ resid, float* __restrict__ out)
{
    __shared__ __align__(16) char smem[33792];
    f16* Ah = (f16*)smem;
    f16* Al = (f16*)(smem + 6144);
    f16* Bh = (f16*)(smem + 12288);
    f16* Bl = (f16*)(smem + 18432);

    const int tid  = threadIdx.x;
    const int wid  = tid >> 6, lane = tid & 63;
    const int ln   = lane & 31, g = lane >> 5;
    const int wm   = wid >> 1, wn = wid & 1;
    const int m0   = blockIdx.y * 128;
    const int n0   = blockIdx.x * 128;
    const int b    = blockIdx.z;

    const int sm = tid >> 1, sko = (tid & 1) * 8;
    const float* wsrc  = W + (size_t)(m0 + sm) * 512 + sko;
    const f16*  bsrcH = OH + ((size_t)(b * 4096) + n0 + sm) * 512 + sko;
    const f16*  bsrcL = OL + ((size_t)(b * 4096) + n0 + sm) * 512 + sko;

    f32x16 accH[2][2], accL[2][2];
    #pragma unroll
    for (int rb = 0; rb < 2; ++rb)
        #pragma unroll
        for (int cb = 0; cb < 2; ++cb)
            #pragma unroll
            for (int r = 0; r < 16; ++r) { accH[rb][cb][r] = 0.0f; accL[rb][cb][r] = 0.0f; }

    for (int k0 = 0; k0 < 512; k0 += 16) {
        {
            float4 v0 = *(const float4*)(wsrc + k0);
            float4 v1 = *(const float4*)(wsrc + k0 + 4);
            float vv[8] = {v0.x, v0.y, v0.z, v0.w, v1.x, v1.y, v1.z, v1.w};
            f16x8 hh, ll;
            #pragma unroll
            for (int j = 0; j < 8; ++j) {
                f16 h = (f16)vv[j];
                hh[j] = h;
                ll[j] = (f16)((vv[j] - (float)h) * 4096.0f);
            }
            *(f16x8*)(Ah + sm * 24 + sko) = hh;
            *(f16x8*)(Al + sm * 24 + sko) = ll;
            *(f16x8*)(Bh + sm * 24 + sko) = *(const f16x8*)(bsrcH + k0);
            *(f16x8*)(Bl + sm * 24 + sko) = *(const f16x8*)(bsrcL + k0);
        }
        __syncthreads();
        f16x8 a_h[2], a_l[2], b_h[2], b_l[2];
        #pragma unroll
        for (int rb = 0; rb < 2; ++rb) {
            int row = wm * 64 + rb * 32 + ln;
            a_h[rb] = *(const f16x8*)(Ah + row * 24 + g * 8);
            a_l[rb] = *(const f16x8*)(Al + row * 24 + g * 8);
        }
        #pragma unroll
        for (int cb = 0; cb < 2; ++cb) {
            int col = wn * 64 + cb * 32 + ln;
            b_h[cb] = *(const f16x8*)(Bh + col * 24 + g * 8);
            b_l[cb] = *(const f16x8*)(Bl + col * 24 + g * 8);
        }
        #pragma unroll
        for (int rb = 0; rb < 2; ++rb)
            #pragma unroll
            for (int cb = 0; cb < 2; ++cb) {
                accH[rb][cb] = __builtin_amdgcn_mfma_f32_32x32x16_f16(a_h[rb], b_h[cb], accH[rb][cb], 0, 0, 0);
                accL[rb][cb] = __builtin_amdgcn_mfma_f32_32x32x16_f16(a_h[rb], b_l[cb], accL[rb][cb], 0, 0, 0);
                accL[rb][cb] = __builtin_amdgcn_mfma_f32_32x32x16_f16(a_l[rb], b_h[cb], accL[rb][cb], 0, 0, 0);
            }
        __syncthreads();
    }

    // ---- epilogue: transpose through LDS, coalesced f32 out += bias+resid
    float* E = (float*)smem + wid * 2112;            // 32 x 66 f32 per wave
    #pragma unroll
    for (int rb = 0; rb < 2; ++rb) {
        #pragma unroll
        for (int cb = 0; cb < 2; ++cb)
            #pragma unroll
            for (int r = 0; r < 16; ++r) {
                int row = (r & 3) + 8 * (r >> 2) + 4 * g;   // verified C mapping
                E[row * 66 + cb * 32 + ln] =
                    accH[rb][cb][r] + accL[rb][cb][r] * (1.0f / 4096.0f);
            }
        __syncthreads();
        #pragma unroll 4
        for (int r = 0; r < 32; ++r) {
            int o = m0 + wm * 64 + rb * 32 + r;
            size_t off = (size_t)b * XSTRIDE + (size_t)o * 4096
                       + n0 + wn * 64 + lane;
            out[off] = E[r * 66 + lane] + bias[o] + resid[off];
        }
        __syncthreads();
    }
}

// ---------------------------------------------------------------------------
// gate2 (exact fp32 path — trunc(tau*32) is discrete, do not perturb).
// ---------------------------------------------------------------------------
__global__ __launch_bounds__(64)
void gate2_kernel(const float* __restrict__ G1, const float* __restrict__ w2,
                  const float* __restrict__ b2, int* __restrict__ KD)
{
    const int b = blockIdx.y;
    const int n = blockIdx.x * 64 + threadIdx.x;
    const float* g = G1 + (size_t)b * G1STRIDE + n;
    float z = b2[0];
    #pragma unroll 8
    for (int c = 0; c < 128; ++c) z += w2[c] * g[(size_t)c * 4096];
    float tau = 1.0f / (1.0f + expf(-z));
    int kd = (int)(tau * 32.0f);
    kd = min(32, max(4, kd));
    KD[b * 4096 + n] = kd;
}

// ---------------------------------------------------------------------------
// R21 select: SINGLE pass via parallel value+index register ladders (the
// LOSSLESS version of R18's failed idea). L[32] stays exact fp32 (med3,
// unchanged); I[32] follows with the same comparisons (2 cmp + 2 cndmask).
// 5 ops/slot vs 1, but pass 2 (half the kernel's fetch/MFMA/scan) is
// DELETED. Strict-> insertion places equal values j-ascending (a later
// equal cannot displace an earlier one) == R14's pass-2 tie order, so
// CV/CI semantics are identical -> absmax must be exactly 0.08642578.
// R18's failure mode (lossy mantissa packing -> boundary flips) does not
// apply: values here are bit-exact.
// Occupancy axis closed: R16 (thinner waves) 1.86x regression; R20
// (waves_per_eu(3,4) -> VGPR 84) 2.6x regression via 13x refetch. This
// kernel needs ~200 VGPRs resident; 2 waves/SIMD is its ceiling.
// Machinery notes (hard-won): scans are _Pragma MACROS (R12 lambdas
// alloca'd L into LDS: 65M bank conflicts); K-frag dbuf as NAMED f16x8
// vars; no scan prefetch (R15 null). waves_per_eu(2,2) pins 256-reg/2-wave.
// ---------------------------------------------------------------------------
#define LOAD_BF(B0,B1,B2,B3,B4,B5,B6,B7, KHP, KLP, CB) do {                   \
    const f16* _ph = (KHP) + (size_t)((CB) * 32 + ln) * 64 + g * 8;           \
    const f16* _pl = (KLP) + (size_t)((CB) * 32 + ln) * 64 + g * 8;           \
    B0 = *(const f16x8*)(_ph);      B1 = *(const f16x8*)(_ph + 16);           \
    B2 = *(const f16x8*)(_ph + 32); B3 = *(const f16x8*)(_ph + 48);           \
    B4 = *(const f16x8*)(_pl);      B5 = *(const f16x8*)(_pl + 16);           \
    B6 = *(const f16x8*)(_pl + 32); B7 = *(const f16x8*)(_pl + 48);           \
} while (0)

// single-pass scan: value+index ladder + lagged thr refresh (expects srow,
// thr, L[], I[], kdm1 in scope). JBASE = global key index of srow[0].
#define P1_SCANI(JBASE) do {                                                  \
    u32 _m = 0;                                                               \
    _Pragma("unroll")                                                         \
    for (int _q = 0; _q < 16; ++_q) {                                         \
        float2 _v = *(const float2*)(srow + 2 * _q);                          \
        _m |= (_v.x > thr) ? (1u << (2 * _q)) : 0u;                           \
        _m |= (_v.y > thr) ? (1u << (2 * _q + 1)) : 0u;                       \
    }                                                                         \
    while (__ballot(_m != 0u)) {                                              \
        bool _act = (_m != 0u);                                               \
        int _j = __builtin_ctz(_m ? _m : 1u);                                 \
        float _c = _act ? srow[_j] : 0.0f;                                    \
        _m &= (_m - 1u);                                                      \
        if (_act && _c > thr) {                                               \
            int _ix = (JBASE) + _j;                                           \
            _Pragma("unroll")                                                 \
            for (int _r = 31; _r >= 1; --_r) {                                \
                bool _gp = _c > L[_r - 1];                                    \
                bool _gc = _c > L[_r];                                        \
                I[_r] = _gp ? I[_r - 1] : (_gc ? _ix : I[_r]);                \
                L[_r] = __builtin_amdgcn_fmed3f(_c, L[_r - 1], L[_r]);        \
            }                                                                 \
            {                                                                 \
                bool _g0 = _c > L[0];                                         \
                I[0] = _g0 ? _ix : I[0];                                      \
                L[0] = _g0 ? _c : L[0];                                       \
            }                                                                 \
        }                                                                     \
    }                                                                         \
    {                                                                         \
        float _th = L[31];                                                    \
        _Pragma("unroll")                                                     \
        for (int _r = 30; _r >= 0; --_r) _th = (kdm1 == _r) ? L[_r] : _th;    \
        thr = _th;                                                            \
    }                                                                         \
} while (0)

__device__ __forceinline__ void score_from(
    f16x8 bh0, f16x8 bh1, f16x8 bh2, f16x8 bh3,
    f16x8 bl0, f16x8 bl1, f16x8 bl2, f16x8 bl3,
    const f16x8 ah[2][4], const f16x8 al[2][4],
    float* __restrict__ Ss, int ln, int g)
{
    __builtin_amdgcn_s_setprio(1);
    #pragma unroll
    for (int rb = 0; rb < 2; ++rb) {
        f32x16 acc, accL;
        #pragma unroll
        for (int r = 0; r < 16; ++r) { acc[r] = 0.0f; accL[r] = 0.0f; }
        // s-order and per-s op order verbatim R11: hh, lh, hl
        acc  = __builtin_amdgcn_mfma_f32_32x32x16_f16(ah[rb][0], bh0, acc,  0, 0, 0);
        accL = __builtin_amdgcn_mfma_f32_32x32x16_f16(al[rb][0], bh0, accL, 0, 0, 0);
        accL = __builtin_amdgcn_mfma_f32_32x32x16_f16(ah[rb][0], bl0, accL, 0, 0, 0);
        acc  = __builtin_amdgcn_mfma_f32_32x32x16_f16(ah[rb][1], bh1, acc,  0, 0, 0);
        accL = __builtin_amdgcn_mfma_f32_32x32x16_f16(al[rb][1], bh1, accL, 0, 0, 0);
        accL = __builtin_amdgcn_mfma_f32_32x32x16_f16(ah[rb][1], bl1, accL, 0, 0, 0);
        acc  = __builtin_amdgcn_mfma_f32_32x32x16_f16(ah[rb][2], bh2, acc,  0, 0, 0);
        accL = __builtin_amdgcn_mfma_f32_32x32x16_f16(al[rb][2], bh2, accL, 0, 0, 0);
        accL = __builtin_amdgcn_mfma_f32_32x32x16_f16(ah[rb][2], bl2, accL, 0, 0, 0);
        acc  = __builtin_amdgcn_mfma_f32_32x32x16_f16(ah[rb][3], bh3, acc,  0, 0, 0);
        accL = __builtin_amdgcn_mfma_f32_32x32x16_f16(al[rb][3], bh3, accL, 0, 0, 0);
        accL = __builtin_amdgcn_mfma_f32_32x32x16_f16(ah[rb][3], bl3, accL, 0, 0, 0);
        // C layout: row=(r&3)+8*(r>>2)+4g, col=ln (verified m74/m101)
        #pragma unroll
        for (int r = 0; r < 16; ++r) {
            int riw = rb * 32 + (r & 3) + 8 * (r >> 2) + 4 * g;
            Ss[riw * 34 + ln] = acc[r] + accL[r] * (1.0f / 4096.0f);
        }
    }
    __builtin_amdgcn_s_setprio(0);
}

// ---------------------------------------------------------------------------
// select v11 (R21): single-pass value+index ladder. One wave/block,
// grid (128,8,2). amdgpu_waves_per_eu(2,2) pins 256-reg/2-wave.
// ---------------------------------------------------------------------------
__global__ __launch_bounds__(64)
__attribute__((amdgpu_waves_per_eu(2, 2)))
void select_kernel(const f16* __restrict__ QH, const f16* __restrict__ QL,
                   const f16* __restrict__ KH, const f16* __restrict__ KL,
                   const int* __restrict__ KD,
                   float* __restrict__ CV, u16* __restrict__ CI)
{
    const int qt = blockIdx.x >> 1;     // 64-row group
    const int hf = blockIdx.x & 1;      // key half
    const int h = blockIdx.y, b = blockIdx.z;
    const size_t base = (size_t)((b * 8 + h) * 4096) * 64;
    const int lane = threadIdx.x;       // 0..63
    const int ln = lane & 31, g = lane >> 5;
    const int nw = qt * 64;
    const int k0base = hf * 2048;

    const int kd = KD[b * 4096 + nw + lane];
    const int kdm1 = kd - 1;

    __shared__ float Ss[64 * 34];       // 64 rows x 32 cols, stride 34

    // resident Q frags: A[m=ln][k=16s+8g+j]
    f16x8 ah[2][4], al[2][4];
    #pragma unroll
    for (int rb = 0; rb < 2; ++rb) {
        const f16* ph = QH + base + (size_t)(nw + rb * 32 + ln) * 64 + g * 8;
        const f16* pl = QL + base + (size_t)(nw + rb * 32 + ln) * 64 + g * 8;
        #pragma unroll
        for (int s = 0; s < 4; ++s) {
            ah[rb][s] = *(const f16x8*)(ph + s * 16);
            al[rb][s] = *(const f16x8*)(pl + s * 16);
        }
    }

    const float INF = __builtin_inff();
    const float* srow = &Ss[lane * 34];

    // named-register double buffer (NO struct/array -> stays in VGPRs)
    f16x8 c0, c1, c2, c3, c4, c5, c6, c7;
    f16x8 n0, n1, n2, n3, n4, n5, n6, n7;

    // ================= single pass: top-kd values + indices =================
    float L[32];
    int   I[32];
    #pragma unroll
    for (int r = 0; r < 32; ++r) { L[r] = -INF; I[r] = 0; }
    float thr = -INF;                    // lagged L[kd-1] (refreshed per block)

    {
        const f16* kh0 = KH + base + (size_t)k0base * 64;
        const f16* kl0 = KL + base + (size_t)k0base * 64;
        LOAD_BF(c0, c1, c2, c3, c4, c5, c6, c7, kh0, kl0, 0);
        for (int t = 0; t < 32; ++t) {
            const f16* kh_t = KH + base + (size_t)(k0base + t * 64) * 64;
            const f16* kl_t = KL + base + (size_t)(k0base + t * 64) * 64;
            const int t1 = (t < 31) ? t + 1 : 31;
            const f16* kh_n = KH + base + (size_t)(k0base + t1 * 64) * 64;
            const f16* kl_n = KL + base + (size_t)(k0base + t1 * 64) * 64;
            // phase cb=0: prefetch (t,cb=1), compute cur, scan
            LOAD_BF(n0, n1, n2, n3, n4, n5, n6, n7, kh_t, kl_t, 1);
            score_from(c0, c1, c2, c3, c4, c5, c6, c7, ah, al, Ss, ln, g);
            P1_SCANI(k0base + t * 64);
            // phase cb=1: prefetch (t+1,cb=0), compute next, scan
            LOAD_BF(c0, c1, c2, c3, c4, c5, c6, c7, kh_n, kl_n, 0);
            score_from(n0, n1, n2, n3, n4, n5, n6, n7, ah, al, Ss, ln, g);
            P1_SCANI(k0base + t * 64 + 32);
        }
    }

    // ================= write top-kd (value, index) =================
    const size_t crow = (size_t)((b * 8 + h) * 4096 + nw + lane);
    float* cvp = CV + crow * 64 + hf * 32;
    u16*   cip = CI + crow * 64 + hf * 32;
    #pragma unroll
    for (int r = 0; r < 32; ++r) {
        if (r < kd) {
            cvp[r] = L[r];
            cip[r] = (u16)I[r];
        }
    }
}

// ---------------------------------------------------------------------------
// merge v3 (R19): sort-insert + softmax + V gather; O emitted as f16 hi/lo
// (OH/OL) in proj's B-operand layout [b*4096+n][c=h*64+d].
// CV slots are now sorted-desc per half (R21); merge is order-agnostic
// (value sort-insert, ties keep earliest slot) -> same result.
// ---------------------------------------------------------------------------
__global__ __launch_bounds__(64)
void merge_kernel(const float* __restrict__ CV, const u16* __restrict__ CI,
                  const int* __restrict__ KD, const f16* __restrict__ VB,
                  f16* __restrict__ OH, f16* __restrict__ OL)
{
    const int tid = threadIdx.x;
    const size_t R0 = (size_t)blockIdx.x * 64;

    __shared__ float Lv[64][66];
    __shared__ u16   Li[64][66];
    __shared__ float Mv[64][34];
    __shared__ u16   Mi[64][34];

    for (int i = 0; i < 64; ++i) {       // coalesced stage
        Lv[i][tid] = CV[(R0 + i) * 64 + tid];
        Li[i][tid] = CI[(R0 + i) * 64 + tid];
    }
    __syncthreads();

    const int myR = (int)R0 + tid;       // = (b*8+h)*4096 + n
    const int b = myR >> 15, n = myR & 4095, h = (myR >> 12) & 7;
    const int kd = KD[b * 4096 + n];

    const float INF = __builtin_inff();
    float L[32]; int I[32];
    #pragma unroll
    for (int r = 0; r < 32; ++r) { L[r] = -INF; I[r] = 0; }

    for (int i = 0; i < 64; ++i) {
        float c = Lv[tid][i];            // NaN filler: all compares false
        int  ix = Li[tid][i];
        if (c > L[31]) {
            #pragma unroll
            for (int r = 31; r >= 1; --r) {
                bool gp = c > L[r - 1];
                bool gc = c > L[r];
                L[r] = gp ? L[r - 1] : (gc ? c : L[r]);
                I[r] = gp ? I[r - 1] : (gc ? ix : I[r]);
            }
            if (c > L[0]) { I[0] = ix; L[0] = c; }
        }
    }

    // park sorted list (register->LDS) for dynamic-index softmax/gather
    #pragma unroll
    for (int r = 0; r < 32; ++r) { Mv[tid][r] = L[r]; Mi[tid][r] = (u16)I[r]; }

    const float mx = Mv[tid][0];
    float sum = 0.0f;
    for (int k = 0; k < kd; ++k) {       // rank order, matches reference
        float e = expf(Mv[tid][k] - mx);
        Mv[tid][k] = e;
        sum += e;
    }
    const float inv = 1.0f / sum;

    float o[64];
    #pragma unroll
    for (int d = 0; d < 64; ++d) o[d] = 0.0f;
    const size_t vbase = (size_t)((b * 8 + h)) * 4096 * 64;
    for (int k = 0; k < kd; ++k) {
        float wgt = Mv[tid][k] * inv;
        const f16* vp = VB + vbase + (size_t)Mi[tid][k] * 64;
        #pragma unroll
        for (int part = 0; part < 8; ++part) {
            f16x8 vv = *(const f16x8*)(vp + part * 8);
            #pragma unroll
            for (int e2 = 0; e2 < 8; ++e2) o[part * 8 + e2] += wgt * (float)vv[e2];
        }
    }

    // hi/lo split store in proj's B layout: [b*4096+n][h*64+d]
    const size_t obase = ((size_t)(b * 4096) + n) * 512 + h * 64;
    #pragma unroll
    for (int part = 0; part < 8; ++part) {
        f16x8 vh, vl;
        #pragma unroll
        for (int e2 = 0; e2 < 8; ++e2) {
            float v = o[part * 8 + e2];
            f16 hh = (f16)v;
            vh[e2] = hh;
            vl[e2] = (f16)((v - (float)hh) * 4096.0f);
        }
        *(f16x8*)(OH + obase + part * 8) = vh;
        *(f16x8*)(OL + obase + part * 8) = vl;
    }
}

// ---------------------------------------------------------------------------
extern "C" void kernel_launch(void* const* d_in, const int* in_sizes, int n_in,
                              void* d_out, int out_size, void* d_ws, size_t ws_size,
                              hipStream_t stream)
{
    const float* x      = (const float*)d_in[0];
    const float* w_qkv  = (const float*)d_in[1];
    const float* w_proj = (const float*)d_in[2];
    const float* b_proj = (const float*)d_in[3];
    const float* w_g1   = (const float*)d_in[4];
    const float* b_g1   = (const float*)d_in[5];
    const float* w_g2   = (const float*)d_in[6];
    const float* b_g2   = (const float*)d_in[7];
    float* out = (float*)d_out;
    float* ws  = (float*)d_ws;

    f16* QH = (f16*)(ws + WS_QH);
    f16* QL = (f16*)(ws + WS_QL);
    f16* KH = (f16*)(ws + WS_KH);
    f16* KL = (f16*)(ws + WS_KL);
    f16* VB = (f16*)(ws + WS_VB);
    float* G1 = ws + WS_G1;
    int*   KD = (int*)(ws + WS_KD);
    u16*   CI = (u16*)(ws + WS_CI);
    float* CV = out;          // d_out as CV scratch (NaN-filled; proj overwrites later)
    f16* OH = (f16*)QH;       // overlay: O (f16 hi/lo) replaces Q hi/lo
    f16* OL = (f16*)QL;

    // d_out first hosts XT (x transposed, f16 hi/lo) for the MFMA qkv GEMM;
    // the NaN memset (CV claim) runs AFTER the consumers.
    f16* XTH = (f16*)out;
    f16* XTL = (f16*)out + 4194304;   // +8 MB (4M f16)

    convert_kernel<<<dim3(64, 8, 2), 256, 0, stream>>>(x, XTH, XTL);
    qkv_gemm<<<dim3(32, 12, 2), 256, 0, stream>>>(
        w_qkv, XTH, XTL, QH, QL, KH, KL, VB);
    gate1_kernel<<<dim3(128, 1, 2), 256, 0, stream>>>(w_g1, x, b_g1, G1);

    // CV = NaN filler (0xFF bytes): unwritten slots never insert in merge
    hipMemsetAsync(CV, 0xFF, (size_t)out_size * sizeof(float), stream);

    gate2_kernel<<<dim3(64, 2), 64, 0, stream>>>(G1, w_g2, b_g2, KD);
    select_kernel<<<dim3(128, 8, 2), 64, 0, stream>>>(QH, QL, KH, KL, KD, CV, CI);
    merge_kernel<<<dim3(1024), 64, 0, stream>>>(CV, CI, KD, VB, OH, OL);
    proj_gemm<<<dim3(32, 4, 2), 256, 0, stream>>>(
        w_proj, OH, OL, b_proj, x, out);
}

// Round 13
// 594.162 us; speedup vs baseline: 1.8868x; 1.4853x over previous
//
#include <hip/hip_runtime.h>
#include <math.h>

// Problem constants: B=2, C=512, H=8 heads, dh=64, N=4096, Kmax=32
#define XSTRIDE  2097152u  // 512*4096 per-batch stride of x / out
#define G1STRIDE 524288u   // 128*4096

typedef _Float16 f16;
typedef f16   f16x8  __attribute__((ext_vector_type(8)));
typedef float f32x16 __attribute__((ext_vector_type(16)));
typedef unsigned int u32;
typedef unsigned short u16;

// ws layout (float offsets). Total 13,639,680 floats = 54.56 MB.
// CV lives in d_out: memset NaN -> select writes -> merge reads -> proj
// overwrites d_out. d_out also hosts XTH/XTL (16 MB) BEFORE the memset.
// merge emits OH/OL (f16 hi/lo, [b*4096+n][c=h*64+d]) overlaid on QH/QL
// (Q dead after select); proj_gemm consumes them on the matrix pipe.
// R22: G1 is gone — gate2 fused into gate1's epilogue (tile has all 128
// channels for its 32 columns); KD written directly.
#define WS_QH 0u          // f16 [2][8][4096][64]; later OH f16 [8192][512]
#define WS_QL 2097152u    // f16 lo parts; later OL
#define WS_KH 4194304u
#define WS_KL 6291456u
#define WS_VB 8388608u    // f16 V
#define WS_G1 10485760u   // (unused as of R22)
#define WS_KD 11534336u   // int [2][4096]
#define WS_CI 11542528u   // u16 [65536 rows][64 slots]

// ---------------------------------------------------------------------------
// R22: gate1+gate2 fused. 128x32 N-tile per block (R17 geometry, 256 blocks
// = 1/CU). Main loop identical to R17 -> ReLU'd G values bitwise-identical.
// Epilogue: park tile in LDS, 32 threads each run gate2's VERBATIM
// ascending-c chain (z = b2 + sum w2[c]*g[c], sequential FP order) -> z
// bitwise-identical -> kd identical. G1 global traffic + gate2 dispatch
// deleted.
// ---------------------------------------------------------------------------
__global__ __launch_bounds__(256)
void gate1_kernel(const float* __restrict__ A,   // w_g1 [128][512]
                  const float* __restrict__ B,   // x [b][512][4096]
                  const float* __restrict__ bias,// b_g1 [128]
                  const float* __restrict__ w2,  // w_g2 [1][128]
                  const float* __restrict__ b2,  // b_g2 [1]
                  int* __restrict__ KD)
{
    const int tid = threadIdx.x;
    const int tm = tid & 15;        // m-group (8 rows each)
    const int tn = tid >> 4;        // n-group (2 cols each, 16 groups)
    const int n0 = blockIdx.x * 32;
    const int b  = blockIdx.z;
    const float* Bb = B + (size_t)b * XSTRIDE;

    __shared__ float As[16][132];
    __shared__ float Bs[16][34];
    __shared__ float G[128][33];    // ReLU'd tile for the fused gate2 dot

    float acc[8][2];
    #pragma unroll
    for (int i = 0; i < 8; ++i) { acc[i][0] = 0.0f; acc[i][1] = 0.0f; }

    for (int k0 = 0; k0 < 512; k0 += 16) {
        {   // A tile [128 m][16 k]
            int id = tid * 2;
            #pragma unroll
            for (int r = 0; r < 2; ++r, ++id) {
                int m = id >> 2, kq = (id & 3) * 4;
                float4 v = *(const float4*)(A + (size_t)m * 512 + k0 + kq);
                As[kq + 0][m] = v.x; As[kq + 1][m] = v.y;
                As[kq + 2][m] = v.z; As[kq + 3][m] = v.w;
            }
        }
        {   // B tile [16 k][32 n]
            int kk = tid >> 4;            // 0..15
            int nn = (tid & 15) * 2;      // 0..30
            float2 v = *(const float2*)(Bb + (size_t)(k0 + kk) * 4096 + n0 + nn);
            Bs[kk][nn] = v.x; Bs[kk][nn + 1] = v.y;
        }
        __syncthreads();
        #pragma unroll
        for (int k = 0; k < 16; ++k) {
            float4 a0 = *(const float4*)(&As[k][tm * 8]);
            float4 a1 = *(const float4*)(&As[k][tm * 8 + 4]);
            float a[8] = {a0.x, a0.y, a0.z, a0.w, a1.x, a1.y, a1.z, a1.w};
            float b0 = Bs[k][tn * 2], b1 = Bs[k][tn * 2 + 1];
            #pragma unroll
            for (int i = 0; i < 8; ++i) {
                acc[i][0] += a[i] * b0;
                acc[i][1] += a[i] * b1;
            }
        }
        __syncthreads();
    }

    // park ReLU'd tile in LDS (values identical to R17's G1 stores)
    #pragma unroll
    for (int i = 0; i < 8; ++i) {
        int o = tm * 8 + i;
        float bi = bias[o];
        G[o][tn * 2 + 0] = fmaxf(acc[i][0] + bi, 0.0f);
        G[o][tn * 2 + 1] = fmaxf(acc[i][1] + bi, 0.0f);
    }
    __syncthreads();

    // fused gate2: verbatim ascending-c sequential chain per column
    if (tid < 32) {
        float z = b2[0];
        #pragma unroll 8
        for (int c = 0; c < 128; ++c) z += w2[c] * G[c][tid];
        float tau = 1.0f / (1.0f + expf(-z));
        int kd = (int)(tau * 32.0f);
        kd = min(32, max(4, kd));
        KD[b * 4096 + n0 + tid] = kd;
    }
}

// ---------------------------------------------------------------------------
// R10: convert+transpose x [b][512 k][4096 n] f32 -> XT [b][4096 n][512 k]
// f16 hi + f16 lo*4096 (exact split). XT lives in d_out (16 MB exactly).
// ---------------------------------------------------------------------------
__global__ __launch_bounds__(256)
void convert_kernel(const float* __restrict__ x,
                    f16* __restrict__ XTH, f16* __restrict__ XTL)
{
    __shared__ float T[64][65];
    const int b = blockIdx.z;
    const int n0 = blockIdx.x * 64, k0 = blockIdx.y * 64;
    const int tid = threadIdx.x;
    const float* xb = x + (size_t)b * XSTRIDE;

    {
        const int c = tid & 63, r = tid >> 6;
        #pragma unroll
        for (int i = 0; i < 16; ++i)
            T[r + i * 4][c] = xb[(size_t)(k0 + r + i * 4) * 4096 + n0 + c];
    }
    __syncthreads();
    const int n = tid >> 2, a = tid & 3;   // thread owns one n-row, 16 k vals
    f16x8 vh[2], vl[2];
    #pragma unroll
    for (int p = 0; p < 2; ++p)
        #pragma unroll
        for (int j = 0; j < 8; ++j) {
            float v = T[a * 16 + p * 8 + j][n];
            f16 h = (f16)v;
            vh[p][j] = h;
            vl[p][j] = (f16)((v - (float)h) * 4096.0f);
        }
    size_t dst = ((size_t)(b * 4096) + n0 + n) * 512 + k0 + a * 16;
    *(f16x8*)(XTH + dst)     = vh[0];
    *(f16x8*)(XTH + dst + 8) = vh[1];
    *(f16x8*)(XTL + dst)     = vl[0];
    *(f16x8*)(XTL + dst + 8) = vl[1];
}

// ---------------------------------------------------------------------------
// R10: qkv GEMM on the matrix pipe (3-product hi/lo f16 MFMA; ll dropped).
// Tile 128x128, K-step 16, 4 waves = 2x2 quadrants of 64x64.
// Fragment layout harness-verified: A[m=ln][k=g*8+j], B[n=ln][k=g*8+j],
// C row=(r&3)+8*(r>>2)+4g, col=ln.
// ---------------------------------------------------------------------------
__global__ __launch_bounds__(256, 2)
void qkv_gemm(const float* __restrict__ W, const f16* __restrict__ XTH,
              const f16* __restrict__ XTL,
              f16* __restrict__ QH, f16* __restrict__ QL,
              f16* __restrict__ KH, f16* __restrict__ KL,
              f16* __restrict__ VB)
{
    __shared__ __align__(16) char smem[33792];
    f16* Ah = (f16*)smem;
    f16* Al = (f16*)(smem + 6144);
    f16* Bh = (f16*)(smem + 12288);
    f16* Bl = (f16*)(smem + 18432);

    const int tid  = threadIdx.x;
    const int wid  = tid >> 6, lane = tid & 63;
    const int ln   = lane & 31, g = lane >> 5;
    const int wm   = wid >> 1, wn = wid & 1;
    const int m0   = blockIdx.y * 128;
    const int n0   = blockIdx.x * 128;
    const int b    = blockIdx.z;

    const int sm = tid >> 1, sko = (tid & 1) * 8;    // staging row / k-octet
    const float* wsrc  = W + (size_t)(m0 + sm) * 512 + sko;
    const f16*  bsrcH = XTH + ((size_t)(b * 4096) + n0 + sm) * 512 + sko;
    const f16*  bsrcL = XTL + ((size_t)(b * 4096) + n0 + sm) * 512 + sko;

    f32x16 accH[2][2], accL[2][2];
    #pragma unroll
    for (int rb = 0; rb < 2; ++rb)
        #pragma unroll
        for (int cb = 0; cb < 2; ++cb)
            #pragma unroll
            for (int r = 0; r < 16; ++r) { accH[rb][cb][r] = 0.0f; accL[rb][cb][r] = 0.0f; }

    for (int k0 = 0; k0 < 512; k0 += 16) {
        {   // A stage + hi/lo convert (lo pre-scaled x4096)
            float4 v0 = *(const float4*)(wsrc + k0);
            float4 v1 = *(const float4*)(wsrc + k0 + 4);
            float vv[8] = {v0.x, v0.y, v0.z, v0.w, v1.x, v1.y, v1.z, v1.w};
            f16x8 hh, ll;
            #pragma unroll
            for (int j = 0; j < 8; ++j) {
                f16 h = (f16)vv[j];
                hh[j] = h;
                ll[j] = (f16)((vv[j] - (float)h) * 4096.0f);
            }
            *(f16x8*)(Ah + sm * 24 + sko) = hh;
            *(f16x8*)(Al + sm * 24 + sko) = ll;
            *(f16x8*)(Bh + sm * 24 + sko) = *(const f16x8*)(bsrcH + k0);
            *(f16x8*)(Bl + sm * 24 + sko) = *(const f16x8*)(bsrcL + k0);
        }
        __syncthreads();
        f16x8 a_h[2], a_l[2], b_h[2], b_l[2];
        #pragma unroll
        for (int rb = 0; rb < 2; ++rb) {
            int row = wm * 64 + rb * 32 + ln;
            a_h[rb] = *(const f16x8*)(Ah + row * 24 + g * 8);
            a_l[rb] = *(const f16x8*)(Al + row * 24 + g * 8);
        }
        #pragma unroll
        for (int cb = 0; cb < 2; ++cb) {
            int col = wn * 64 + cb * 32 + ln;
            b_h[cb] = *(const f16x8*)(Bh + col * 24 + g * 8);
            b_l[cb] = *(const f16x8*)(Bl + col * 24 + g * 8);
        }
        #pragma unroll
        for (int rb = 0; rb < 2; ++rb)
            #pragma unroll
            for (int cb = 0; cb < 2; ++cb) {
                accH[rb][cb] = __builtin_amdgcn_mfma_f32_32x32x16_f16(a_h[rb], b_h[cb], accH[rb][cb], 0, 0, 0);
                accL[rb][cb] = __builtin_amdgcn_mfma_f32_32x32x16_f16(a_h[rb], b_l[cb], accL[rb][cb], 0, 0, 0);
                accL[rb][cb] = __builtin_amdgcn_mfma_f32_32x32x16_f16(a_l[rb], b_h[cb], accL[rb][cb], 0, 0, 0);
            }
        __syncthreads();
    }

    // ---- epilogue: per-wave transpose through LDS, then hi/lo split stores
    const int which = m0 >> 9;                       // 0=q 1=k 2=v
    const float scale = (which == 0) ? 0.125f : 1.0f;
    const int hh_ = ((m0 & 511) >> 6) + wm;          // head (block-uniform per wave)
    const size_t rowb0 = (size_t)(b * 8 + hh_) * 4096 + n0 + wn * 64 + lane;
    float* E = (float*)smem + wid * 2112;            // 32 x 66 f32 per wave

    #pragma unroll
    for (int rb = 0; rb < 2; ++rb) {
        #pragma unroll
        for (int cb = 0; cb < 2; ++cb)
            #pragma unroll
            for (int r = 0; r < 16; ++r) {
                int row = (r & 3) + 8 * (r >> 2) + 4 * g;   // verified C mapping
                E[row * 66 + cb * 32 + ln] =
                    accH[rb][cb][r] + accL[rb][cb][r] * (1.0f / 4096.0f);
            }
        __syncthreads();
        const int dbase = rb * 32;
        if (which == 2) {
            #pragma unroll
            for (int oct = 0; oct < 4; ++oct) {
                f16x8 vv;
                #pragma unroll
                for (int j = 0; j < 8; ++j) vv[j] = (f16)E[(oct * 8 + j) * 66 + lane];
                *(f16x8*)(VB + rowb0 * 64 + dbase + oct * 8) = vv;
            }
        } else {
            f16* DH = which ? KH : QH;
            f16* DL = which ? KL : QL;
            #pragma unroll
            for (int oct = 0; oct < 4; ++oct) {
                f16x8 vh, vl;
                #pragma unroll
                for (int j = 0; j < 8; ++j) {
                    float xx = E[(oct * 8 + j) * 66 + lane] * scale;
                    f16 h = (f16)xx;
                    vh[j] = h;
                    vl[j] = (f16)((xx - (float)h) * 4096.0f);
                }
                *(f16x8*)(DH + rowb0 * 64 + dbase + oct * 8) = vh;
                *(f16x8*)(DL + rowb0 * 64 + dbase + oct * 8) = vl;
            }
        }
        __syncthreads();
    }
}

// ---------------------------------------------------------------------------
// R19: proj GEMM on the matrix pipe — mechanical mirror of qkv_gemm.
// A = w_proj (hi/lo in-kernel), B = OH/OL (merge output, [b*4096+n][h*64+d]).
// Epilogue: LDS transpose then coalesced f32 stores of C + bias + resid.
// ---------------------------------------------------------------------------
__global__ __launch_bounds__(256, 2)
void proj_gemm(const float* __restrict__ W, const f16* __restrict__ OH,
               const f16* __restrict__ OL, const float* __restrict__ bias,
               const float* __restrict__ resid, float* __restrict__ out)
{
    __shared__ __align__(16) char smem[33792];
    f16* Ah = (f16*)smem;
    f16* Al = (f16*)(smem + 6144);
    f16* Bh = (f16*)(smem + 12288);
    f16* Bl = (f16*)(smem + 18432);

    const int tid  = threadIdx.x;
    const int wid  = tid >> 6, lane = tid & 63;
    const int ln   = lane & 31, g = lane >> 5;
    const int wm   = wid >> 1, wn = wid & 1;
    const int m0   = blockIdx.y * 128;
    const int n0   = blockIdx.x * 128;
    const int b    = blockIdx.z;

    const int sm = tid >> 1, sko = (tid & 1) * 8;
    const float* wsrc  = W + (size_t)(m0 + sm) * 512 + sko;
    const f16*  bsrcH = OH + ((size_t)(b * 4096) + n0 + sm) * 512 + sko;
    const f16*  bsrcL = OL + ((size_t)(b * 4096) + n0 + sm) * 512 + sko;

    f32x16 accH[2][2], accL[2][2];
    #pragma unroll
    for (int rb = 0; rb < 2; ++rb)
        #pragma unroll
        for (int cb = 0; cb < 2; ++cb)
            #pragma unroll
            for (int r = 0; r < 16; ++r) { accH[rb][cb][r] = 0.0f; accL[rb][cb][r] = 0.0f; }

    for (int k0 = 0; k0 < 512; k0 += 16) {
        {
            float4 v0 = *(const float4*)(wsrc + k0);
            float4 v1 = *(const float4*)(wsrc + k0 + 4);
            float vv[8] = {v0.x, v0.y, v0.z, v0.w, v1.x, v1.y, v1.z, v1.w};
            f16x8 hh, ll;
            #pragma unroll
            for (int j = 0; j < 8; ++j) {
                f16 h = (f16)vv[j];
                hh[j] = h;
                ll[j] = (f16)((vv[j] - (float)h) * 4096.0f);
            }
            *(f16x8*)(Ah + sm * 24 + sko) = hh;
            *(f16x8*)(Al + sm * 24 + sko) = ll;
            *(f16x8*)(Bh + sm * 24 + sko) = *(const f16x8*)(bsrcH + k0);
            *(f16x8*)(Bl + sm * 24 + sko) = *(const f16x8*)(bsrcL + k0);
        }
        __syncthreads();
        f16x8 a_h[2], a_l[2], b_h[2], b_l[2];
        #pragma unroll
        for (int rb = 0; rb < 2; ++rb) {
            int row = wm * 64 + rb * 32 + ln;
            a_h[rb] = *(const f16x8*)(Ah + row * 24 + g * 8);
            a_l[rb] = *(const f16x8*)(Al + row * 24 + g * 8);
        }
        #pragma unroll
        for (int cb = 0; cb < 2; ++cb) {
            int col = wn * 64 + cb * 32 + ln;
            b_h[cb] = *(const f16x8*)(Bh + col * 24 + g * 8);
            b_l[cb] = *(const f16x8*)(Bl + col * 24 + g * 8);
        }
        #pragma unroll
        for (int rb = 0; rb < 2; ++rb)
            #pragma unroll
            for (int cb = 0; cb < 2; ++cb) {
                accH[rb][cb] = __builtin_amdgcn_mfma_f32_32x32x16_f16(a_h[rb], b_h[cb], accH[rb][cb], 0, 0, 0);
                accL[rb][cb] = __builtin_amdgcn_mfma_f32_32x32x16_f16(a_h[rb], b_l[cb], accL[rb][cb], 0, 0, 0);
                accL[rb][cb] = __builtin_amdgcn_mfma_f32_32x32x16_f16(a_l[rb], b_h[cb], accL[rb][cb], 0, 0, 0);
            }
        __syncthreads();
    }

    // ---- epilogue: transpose through LDS, coalesced f32 out += bias+resid
    float* E = (float*)smem + wid * 2112;            // 32 x 66 f32 per wave
    #pragma unroll
    for (int rb = 0; rb < 2; ++rb) {
        #pragma unroll
        for (int cb = 0; cb < 2; ++cb)
            #pragma unroll
            for (int r = 0; r < 16; ++r) {
                int row = (r & 3) + 8 * (r >> 2) + 4 * g;   // verified C mapping
                E[row * 66 + cb * 32 + ln] =
                    accH[rb][cb][r] + accL[rb][cb][r] * (1.0f / 4096.0f);
            }
        __syncthreads();
        #pragma unroll 4
        for (int r = 0; r < 32; ++r) {
            int o = m0 + wm * 64 + rb * 32 + r;
            size_t off = (size_t)b * XSTRIDE + (size_t)o * 4096
                       + n0 + wn * 64 + lane;
            out[off] = E[r * 66 + lane] + bias[o] + resid[off];
        }
        __syncthreads();
    }
}

// ---------------------------------------------------------------------------
// R22 select = R14 verbatim (best measured: 334-339 µs, absmax 0.08642578).
// Select-restructure ledger (all reverted): R15 prefetch null (allocator
// re-sinks loads at its hard 128-VGPR ceiling); R16 32-row split 1.86x
// (phases latency-bound); R18 index-in-mantissa 0.459 absmax (lossy);
// R20 waves_per_eu(3,4) 2.6x (VGPR 84 -> 13x refetch); R21 value+index
// ladder 1.8x (I[32] -> scratch spill, FETCH 82->272 MB). This form is a
// constrained local optimum at 128 regs / 2 waves/SIMD.
// Structure notes: scans are _Pragma MACROS (R12 lambdas alloca'd L[32]
// into LDS: 65M bank conflicts); K-frag dbuf as NAMED f16x8 vars.
// ---------------------------------------------------------------------------
#define LOAD_BF(B0,B1,B2,B3,B4,B5,B6,B7, KHP, KLP, CB) do {                   \
    const f16* _ph = (KHP) + (size_t)((CB) * 32 + ln) * 64 + g * 8;           \
    const f16* _pl = (KLP) + (size_t)((CB) * 32 + ln) * 64 + g * 8;           \
    B0 = *(const f16x8*)(_ph);      B1 = *(const f16x8*)(_ph + 16);           \
    B2 = *(const f16x8*)(_ph + 32); B3 = *(const f16x8*)(_ph + 48);           \
    B4 = *(const f16x8*)(_pl);      B5 = *(const f16x8*)(_pl + 16);           \
    B6 = *(const f16x8*)(_pl + 32); B7 = *(const f16x8*)(_pl + 48);           \
} while (0)

// pass-1 scan of Ss: med3 ladder + lagged thr refresh (expects srow, thr,
// L[], kdm1 in scope)
#define P1_SCAN() do {                                                        \
    u32 _m = 0;                                                               \
    _Pragma("unroll")                                                         \
    for (int _q = 0; _q < 16; ++_q) {                                         \
        float2 _v = *(const float2*)(srow + 2 * _q);                          \
        _m |= (_v.x > thr) ? (1u << (2 * _q)) : 0u;                           \
        _m |= (_v.y > thr) ? (1u << (2 * _q + 1)) : 0u;                       \
    }                                                                         \
    while (__ballot(_m != 0u)) {                                              \
        bool _act = (_m != 0u);                                               \
        int _j = __builtin_ctz(_m ? _m : 1u);                                 \
        float _c = _act ? srow[_j] : 0.0f;                                    \
        _m &= (_m - 1u);                                                      \
        if (_act && _c > thr) {                                               \
            _Pragma("unroll")                                                 \
            for (int _r = 31; _r >= 1; --_r)                                  \
                L[_r] = __builtin_amdgcn_fmed3f(_c, L[_r - 1], L[_r]);        \
            L[0] = fmaxf(L[0], _c);                                           \
        }                                                                     \
    }                                                                         \
    {                                                                         \
        float _th = L[31];                                                    \
        _Pragma("unroll")                                                     \
        for (int _r = 30; _r >= 0; --_r) _th = (kdm1 == _r) ? L[_r] : _th;    \
        thr = _th;                                                            \
    }                                                                         \
} while (0)

// pass-2 scan: capture qualifying (val,idx) (expects srow, theta, eqNeed,
// cnt, eqc, cvp, cip in scope)
#define P2_SCAN(JBASE) do {                                                   \
    u32 _m = 0;                                                               \
    _Pragma("unroll")                                                         \
    for (int _q = 0; _q < 16; ++_q) {                                         \
        float2 _v = *(const float2*)(srow + 2 * _q);                          \
        _m |= (_v.x >= theta) ? (1u << (2 * _q)) : 0u;                        \
        _m |= (_v.y >= theta) ? (1u << (2 * _q + 1)) : 0u;                    \
    }                                                                         \
    while (__ballot(_m != 0u)) {                                              \
        bool _act = (_m != 0u);                                               \
        int _j = __builtin_ctz(_m ? _m : 1u);                                 \
        float _c = _act ? srow[_j] : 0.0f;                                    \
        _m &= (_m - 1u);                                                      \
        if (_act) {                                                           \
            bool _isGT = _c > theta;                                          \
            bool _doA = (_isGT || eqc < eqNeed) && cnt < 32;                  \
            if (_doA) {                                                       \
                cvp[cnt] = _c;                                                \
                cip[cnt] = (u16)((JBASE) + _j);                               \
                cnt++;                                                        \
                if (!_isGT) eqc++;                                            \
            }                                                                 \
        }                                                                     \
    }                                                                         \
} while (0)

__device__ __forceinline__ void score_from(
    f16x8 bh0, f16x8 bh1, f16x8 bh2, f16x8 bh3,
    f16x8 bl0, f16x8 bl1, f16x8 bl2, f16x8 bl3,
    const f16x8 ah[2][4], const f16x8 al[2][4],
    float* __restrict__ Ss, int ln, int g)
{
    __builtin_amdgcn_s_setprio(1);
    #pragma unroll
    for (int rb = 0; rb < 2; ++rb) {
        f32x16 acc, accL;
        #pragma unroll
        for (int r = 0; r < 16; ++r) { acc[r] = 0.0f; accL[r] = 0.0f; }
        // s-order and per-s op order verbatim R11: hh, lh, hl
        acc  = __builtin_amdgcn_mfma_f32_32x32x16_f16(ah[rb][0], bh0, acc,  0, 0, 0);
        accL = __builtin_amdgcn_mfma_f32_32x32x16_f16(al[rb][0], bh0, accL, 0, 0, 0);
        accL = __builtin_amdgcn_mfma_f32_32x32x16_f16(ah[rb][0], bl0, accL, 0, 0, 0);
        acc  = __builtin_amdgcn_mfma_f32_32x32x16_f16(ah[rb][1], bh1, acc,  0, 0, 0);
        accL = __builtin_amdgcn_mfma_f32_32x32x16_f16(al[rb][1], bh1, accL, 0, 0, 0);
        accL = __builtin_amdgcn_mfma_f32_32x32x16_f16(ah[rb][1], bl1, accL, 0, 0, 0);
        acc  = __builtin_amdgcn_mfma_f32_32x32x16_f16(ah[rb][2], bh2, acc,  0, 0, 0);
        accL = __builtin_amdgcn_mfma_f32_32x32x16_f16(al[rb][2], bh2, accL, 0, 0, 0);
        accL = __builtin_amdgcn_mfma_f32_32x32x16_f16(ah[rb][2], bl2, accL, 0, 0, 0);
        acc  = __builtin_amdgcn_mfma_f32_32x32x16_f16(ah[rb][3], bh3, acc,  0, 0, 0);
        accL = __builtin_amdgcn_mfma_f32_32x32x16_f16(al[rb][3], bh3, accL, 0, 0, 0);
        accL = __builtin_amdgcn_mfma_f32_32x32x16_f16(ah[rb][3], bl3, accL, 0, 0, 0);
        // C layout: row=(r&3)+8*(r>>2)+4g, col=ln (verified m74/m101)
        #pragma unroll
        for (int r = 0; r < 16; ++r) {
            int riw = rb * 32 + (r & 3) + 8 * (r >> 2) + 4 * g;
            Ss[riw * 34 + ln] = acc[r] + accL[r] * (1.0f / 4096.0f);
        }
    }
    __builtin_amdgcn_s_setprio(0);
}

// ---------------------------------------------------------------------------
// select v7 (R14 structure): two-pass, spill-free, register-resident K-frag
// pipeline, scan bodies as macros. One wave/block, grid (128,8,2).
// amdgpu_waves_per_eu(2,2) pins 256-reg/2-wave.
// ---------------------------------------------------------------------------
__global__ __launch_bounds__(64)
__attribute__((amdgpu_waves_per_eu(2, 2)))
void select_kernel(const f16* __restrict__ QH, const f16* __restrict__ QL,
                   const f16* __restrict__ KH, const f16* __restrict__ KL,
                   const int* __restrict__ KD,
                   float* __restrict__ CV, u16* __restrict__ CI)
{
    const int qt = blockIdx.x >> 1;     // 64-row group
    const int hf = blockIdx.x & 1;      // key half
    const int h = blockIdx.y, b = blockIdx.z;
    const size_t base = (size_t)((b * 8 + h) * 4096) * 64;
    const int lane = threadIdx.x;       // 0..63
    const int ln = lane & 31, g = lane >> 5;
    const int nw = qt * 64;
    const int k0base = hf * 2048;

    const int kd = KD[b * 4096 + nw + lane];
    const int kdm1 = kd - 1;

    __shared__ float Ss[64 * 34];       // 64 rows x 32 cols, stride 34

    // resident Q frags: A[m=ln][k=16s+8g+j]
    f16x8 ah[2][4], al[2][4];
    #pragma unroll
    for (int rb = 0; rb < 2; ++rb) {
        const f16* ph = QH + base + (size_t)(nw + rb * 32 + ln) * 64 + g * 8;
        const f16* pl = QL + base + (size_t)(nw + rb * 32 + ln) * 64 + g * 8;
        #pragma unroll
        for (int s = 0; s < 4; ++s) {
            ah[rb][s] = *(const f16x8*)(ph + s * 16);
            al[rb][s] = *(const f16x8*)(pl + s * 16);
        }
    }

    const float INF = __builtin_inff();
    const float* srow = &Ss[lane * 34];

    // named-register double buffer (NO struct/array -> stays in VGPRs)
    f16x8 c0, c1, c2, c3, c4, c5, c6, c7;
    f16x8 n0, n1, n2, n3, n4, n5, n6, n7;

    // ================= pass 1: values-only top-kd =================
    float L[32];
    #pragma unroll
    for (int r = 0; r < 32; ++r) L[r] = -INF;
    float thr = -INF;                    // lagged L[kd-1] (refreshed per block)

    {
        const f16* kh0 = KH + base + (size_t)k0base * 64;
        const f16* kl0 = KL + base + (size_t)k0base * 64;
        LOAD_BF(c0, c1, c2, c3, c4, c5, c6, c7, kh0, kl0, 0);
        for (int t = 0; t < 32; ++t) {
            const f16* kh_t = KH + base + (size_t)(k0base + t * 64) * 64;
            const f16* kl_t = KL + base + (size_t)(k0base + t * 64) * 64;
            const int t1 = (t < 31) ? t + 1 : 31;
            const f16* kh_n = KH + base + (size_t)(k0base + t1 * 64) * 64;
            const f16* kl_n = KL + base + (size_t)(k0base + t1 * 64) * 64;
            // phase cb=0: prefetch (t,cb=1), compute cur, scan
            LOAD_BF(n0, n1, n2, n3, n4, n5, n6, n7, kh_t, kl_t, 1);
            score_from(c0, c1, c2, c3, c4, c5, c6, c7, ah, al, Ss, ln, g);
            P1_SCAN();
            // phase cb=1: prefetch (t+1,cb=0), compute next, scan
            LOAD_BF(c0, c1, c2, c3, c4, c5, c6, c7, kh_n, kl_n, 0);
            score_from(n0, n1, n2, n3, n4, n5, n6, n7, ah, al, Ss, ln, g);
            P1_SCAN();
        }
    }
    const float theta = thr;             // exact kd-th largest of this half
    int cntGT = 0;
    #pragma unroll
    for (int r = 0; r < 32; ++r) cntGT += ((r < kd) && (L[r] > theta)) ? 1 : 0;
    const int eqNeed = kd - cntGT;

    // ================= pass 2: capture indices =================
    const size_t crow = (size_t)((b * 8 + h) * 4096 + nw + lane);
    float* cvp = CV + crow * 64 + hf * 32;
    u16*   cip = CI + crow * 64 + hf * 32;
    int cnt = 0, eqc = 0;

    {
        const f16* kh0 = KH + base + (size_t)k0base * 64;
        const f16* kl0 = KL + base + (size_t)k0base * 64;
        LOAD_BF(c0, c1, c2, c3, c4, c5, c6, c7, kh0, kl0, 0);
        for (int t = 0; t < 32; ++t) {
            const f16* kh_t = KH + base + (size_t)(k0base + t * 64) * 64;
            const f16* kl_t = KL + base + (size_t)(k0base + t * 64) * 64;
            const int t1 = (t < 31) ? t + 1 : 31;
            const f16* kh_n = KH + base + (size_t)(k0base + t1 * 64) * 64;
            const f16* kl_n = KL + base + (size_t)(k0base + t1 * 64) * 64;
            LOAD_BF(n0, n1, n2, n3, n4, n5, n6, n7, kh_t, kl_t, 1);
            score_from(c0, c1, c2, c3, c4, c5, c6, c7, ah, al, Ss, ln, g);
            P2_SCAN(k0base + t * 64);
            LOAD_BF(c0, c1, c2, c3, c4, c5, c6, c7, kh_n, kl_n, 0);
            score_from(n0, n1, n2, n3, n4, n5, n6, n7, ah, al, Ss, ln, g);
            P2_SCAN(k0base + t * 64 + 32);
        }
    }
}

// ---------------------------------------------------------------------------
// merge v3 (R19): sort-insert + softmax + V gather; O emitted as f16 hi/lo
// (OH/OL) in proj's B-operand layout [b*4096+n][c=h*64+d].
// ---------------------------------------------------------------------------
__global__ __launch_bounds__(64)
void merge_kernel(const float* __restrict__ CV, const u16* __restrict__ CI,
                  const int* __restrict__ KD, const f16* __restrict__ VB,
                  f16* __restrict__ OH, f16* __restrict__ OL)
{
    const int tid = threadIdx.x;
    const size_t R0 = (size_t)blockIdx.x * 64;

    __shared__ float Lv[64][66];
    __shared__ u16   Li[64][66];
    __shared__ float Mv[64][34];
    __shared__ u16   Mi[64][34];

    for (int i = 0; i < 64; ++i) {       // coalesced stage
        Lv[i][tid] = CV[(R0 + i) * 64 + tid];
        Li[i][tid] = CI[(R0 + i) * 64 + tid];
    }
    __syncthreads();

    const int myR = (int)R0 + tid;       // = (b*8+h)*4096 + n
    const int b = myR >> 15, n = myR & 4095, h = (myR >> 12) & 7;
    const int kd = KD[b * 4096 + n];

    const float INF = __builtin_inff();
    float L[32]; int I[32];
    #pragma unroll
    for (int r = 0; r < 32; ++r) { L[r] = -INF; I[r] = 0; }

    for (int i = 0; i < 64; ++i) {
        float c = Lv[tid][i];            // NaN filler: all compares false
        int  ix = Li[tid][i];
        if (c > L[31]) {
            #pragma unroll
            for (int r = 31; r >= 1; --r) {
                bool gp = c > L[r - 1];
                bool gc = c > L[r];
                L[r] = gp ? L[r - 1] : (gc ? c : L[r]);
                I[r] = gp ? I[r - 1] : (gc ? ix : I[r]);
            }
            if (c > L[0]) { I[0] = ix; L[0] = c; }
        }
    }

    // park sorted list (register->LDS) for dynamic-index softmax/gather
    #pragma unroll
    for (int r = 0; r < 32; ++r) { Mv[tid][r] = L[r]; Mi[tid][r] = (u16)I[r]; }

    const float mx = Mv[tid][0];
    float sum = 0.0f;
    for (int k = 0; k < kd; ++k) {       // rank order, matches reference
        float e = expf(Mv[tid][k] - mx);
        Mv[tid][k] = e;
        sum += e;
    }
    const float inv = 1.0f / sum;

    float o[64];
    #pragma unroll
    for (int d = 0; d < 64; ++d) o[d] = 0.0f;
    const size_t vbase = (size_t)((b * 8 + h)) * 4096 * 64;
    for (int k = 0; k < kd; ++k) {
        float wgt = Mv[tid][k] * inv;
        const f16* vp = VB + vbase + (size_t)Mi[tid][k] * 64;
        #pragma unroll
        for (int part = 0; part < 8; ++part) {
            f16x8 vv = *(const f16x8*)(vp + part * 8);
            #pragma unroll
            for (int e2 = 0; e2 < 8; ++e2) o[part * 8 + e2] += wgt * (float)vv[e2];
        }
    }

    // hi/lo split store in proj's B layout: [b*4096+n][h*64+d]
    const size_t obase = ((size_t)(b * 4096) + n) * 512 + h * 64;
    #pragma unroll
    for (int part = 0; part < 8; ++part) {
        f16x8 vh, vl;
        #pragma unroll
        for (int e2 = 0; e2 < 8; ++e2) {
            float v = o[part * 8 + e2];
            f16 hh = (f16)v;
            vh[e2] = hh;
            vl[e2] = (f16)((v - (float)hh) * 4096.0f);
        }
        *(f16x8*)(OH + obase + part * 8) = vh;
        *(f16x8*)(OL + obase + part * 8) = vl;
    }
}

// ---------------------------------------------------------------------------
extern "C" void kernel_launch(void* const* d_in, const int* in_sizes, int n_in,
                              void* d_out, int out_size, void* d_ws, size_t ws_size,
                              hipStream_t stream)
{
    const float* x      = (const float*)d_in[0];
    const float* w_qkv  = (const float*)d_in[1];
    const float* w_proj = (const float*)d_in[2];
    const float* b_proj = (const float*)d_in[3];
    const float* w_g1   = (const float*)d_in[4];
    const float* b_g1   = (const float*)d_in[5];
    const float* w_g2   = (const float*)d_in[6];
    const float* b_g2   = (const float*)d_in[7];
    float* out = (float*)d_out;
    float* ws  = (float*)d_ws;

    f16* QH = (f16*)(ws + WS_QH);
    f16* QL = (f16*)(ws + WS_QL);
    f16* KH = (f16*)(ws + WS_KH);
    f16* KL = (f16*)(ws + WS_KL);
    f16* VB = (f16*)(ws + WS_VB);
    int*   KD = (int*)(ws + WS_KD);
    u16*   CI = (u16*)(ws + WS_CI);
    float* CV = out;          // d_out as CV scratch (NaN-filled; proj overwrites later)
    f16* OH = (f16*)QH;       // overlay: O (f16 hi/lo) replaces Q hi/lo
    f16* OL = (f16*)QL;

    // d_out first hosts XT (x transposed, f16 hi/lo) for the MFMA qkv GEMM;
    // the NaN memset (CV claim) runs AFTER the consumers.
    f16* XTH = (f16*)out;
    f16* XTL = (f16*)out + 4194304;   // +8 MB (4M f16)

    convert_kernel<<<dim3(64, 8, 2), 256, 0, stream>>>(x, XTH, XTL);
    qkv_gemm<<<dim3(32, 12, 2), 256, 0, stream>>>(
        w_qkv, XTH, XTL, QH, QL, KH, KL, VB);
    gate1_kernel<<<dim3(128, 1, 2), 256, 0, stream>>>(
        w_g1, x, b_g1, w_g2, b_g2, KD);

    // CV = NaN filler (0xFF bytes): unwritten slots never insert in merge
    hipMemsetAsync(CV, 0xFF, (size_t)out_size * sizeof(float), stream);

    select_kernel<<<dim3(128, 8, 2), 64, 0, stream>>>(QH, QL, KH, KL, KD, CV, CI);
    merge_kernel<<<dim3(1024), 64, 0, stream>>>(CV, CI, KD, VB, OH, OL);
    proj_gemm<<<dim3(32, 4, 2), 256, 0, stream>>>(
        w_proj, OH, OL, b_proj, x, out);
}